// Round 14
// baseline (547.183 us; speedup 1.0000x reference)
//
#include <hip/hip_runtime.h>
#include <hip/hip_bf16.h>

#define B_ 4
#define S_ 2048
#define D_ 512
#define H_ 8
#define HD_ 64
#define L_ 2
#define V_ 30000
#define NPATCH_ 16
#define PLEN_ 128

typedef short bf16x8 __attribute__((ext_vector_type(8)));
typedef float f32x4 __attribute__((ext_vector_type(4)));

__device__ __forceinline__ unsigned short f2bf(float f) {
    unsigned u = __float_as_uint(f);
    return (unsigned short)((u + 0x7FFFu + ((u >> 16) & 1u)) >> 16);   // RNE
}
__device__ __forceinline__ float bf2f(unsigned short u) {
    return __uint_as_float(((unsigned int)u) << 16);
}

// ---------------- merged f32 -> bf16 weight casts (1 launch) ----------------
#define C0_ (2*1536*512/4)
#define C1_ (2*512*512/4)
#define C2_ (2*2048*512/4)
#define C3_ (2*512*2048/4)
#define C4_ (1024*512/4)
__global__ __launch_bounds__(256) void cast5_kernel(
    const float* __restrict__ s0, const float* __restrict__ s1,
    const float* __restrict__ s2, const float* __restrict__ s3,
    const float* __restrict__ s4,
    unsigned short* __restrict__ d0, unsigned short* __restrict__ d1,
    unsigned short* __restrict__ d2, unsigned short* __restrict__ d3,
    unsigned short* __restrict__ d4)
{
    int i = blockIdx.x * 256 + threadIdx.x;
    const float* s; unsigned short* d;
    if      (i < C0_)                  { s = s0; d = d0; }
    else if ((i -= C0_) < C1_)         { s = s1; d = d1; }
    else if ((i -= C1_) < C2_)         { s = s2; d = d2; }
    else if ((i -= C2_) < C3_)         { s = s3; d = d3; }
    else if ((i -= C3_) < C4_)         { s = s4; d = d4; }
    else return;
    const float4 v = *reinterpret_cast<const float4*>(s + (size_t)i * 4);
    ushort4 o;
    o.x = f2bf(v.x); o.y = f2bf(v.y); o.z = f2bf(v.z); o.w = f2bf(v.w);
    *reinterpret_cast<ushort4*>(d + (size_t)i * 4) = o;
}

// ---------------- embed + n-gram hash add (f32 + bf16 shadow) -------------
__global__ __launch_bounds__(128) void embed_ngram_kernel(
    const int* __restrict__ bytes, const float* __restrict__ byte_emb,
    const float* __restrict__ ng_emb, float* __restrict__ x,
    unsigned short* __restrict__ xb)
{
    const int bs = blockIdx.x;
    const int s  = bs % S_;
    const int b  = bs / S_;
    const int d  = threadIdx.x * 4;
    const int* brow = bytes + (size_t)b * S_;

    const int c = brow[s];
    float4 v = *reinterpret_cast<const float4*>(byte_emb + (size_t)c * D_ + d);

    if (s >= 2) {
        int h = (brow[s-2]*961 + brow[s-1]*31 + brow[s]) % V_;
        const float4 g = *reinterpret_cast<const float4*>(ng_emb + ((size_t)0*V_ + h)*D_ + d);
        v.x += 0.25f*g.x; v.y += 0.25f*g.y; v.z += 0.25f*g.z; v.w += 0.25f*g.w;
    }
    if (s >= 3) {
        int h = (brow[s-3]*29791 + brow[s-2]*961 + brow[s-1]*31 + brow[s]) % V_;
        const float4 g = *reinterpret_cast<const float4*>(ng_emb + ((size_t)1*V_ + h)*D_ + d);
        v.x += 0.25f*g.x; v.y += 0.25f*g.y; v.z += 0.25f*g.z; v.w += 0.25f*g.w;
    }
    if (s >= 4) {
        int h = (brow[s-4]*23521 + brow[s-3]*29791 + brow[s-2]*961 + brow[s-1]*31 + brow[s]) % V_;
        const float4 g = *reinterpret_cast<const float4*>(ng_emb + ((size_t)2*V_ + h)*D_ + d);
        v.x += 0.25f*g.x; v.y += 0.25f*g.y; v.z += 0.25f*g.z; v.w += 0.25f*g.w;
    }
    *reinterpret_cast<float4*>(x + (size_t)bs * D_ + d) = v;
    ushort4 o;
    o.x = f2bf(v.x); o.y = f2bf(v.y); o.z = f2bf(v.z); o.w = f2bf(v.w);
    *reinterpret_cast<ushort4*>(xb + (size_t)bs * D_ + d) = o;
}

// ---------------- MFMA bf16 GEMM: Y = X @ W^T + bias [,relu][,+resid] ------
template<int DO_RELU, int BF16OUT, int BN, int VT, int RESID>
__global__ __launch_bounds__(256) void mgemm_kernel(
    const unsigned short* __restrict__ Xb, const unsigned short* __restrict__ Wb,
    const float* __restrict__ bias, void* __restrict__ Yout,
    unsigned short* __restrict__ vtb, const float* __restrict__ resid,
    int M, int N, int K)
{
    constexpr int NT  = BN / 32;
    constexpr int NLB = BN / 32;
    __shared__ unsigned short As[128*64];
    __shared__ unsigned short Bs[BN*64];

    const int t    = threadIdx.x;
    const int lane = t & 63;
    const int w    = t >> 6;

    const int nwg = gridDim.x * gridDim.y;
    const int bid = blockIdx.y * gridDim.x + blockIdx.x;
    const int swz = (bid & 7) * (nwg >> 3) + (bid >> 3);
    const int bx  = swz % gridDim.x, by = swz / gridDim.x;

    const int bm   = by * 128, bn = bx * BN;
    const int l15  = lane & 15, lg = lane >> 4;
    const int wr   = w >> 1, wc = w & 1;

    int srow[4], scol[4];
#pragma unroll
    for (int i = 0; i < 4; ++i) {
        const int off = w*1024 + i*4096 + lane*16;
        srow[i] = off >> 7;
        scol[i] = ((off >> 4) & 7) ^ (srow[i] & 7);
    }

    f32x4 acc[4][NT];
#pragma unroll
    for (int mt = 0; mt < 4; ++mt)
#pragma unroll
        for (int nt = 0; nt < NT; ++nt) acc[mt][nt] = (f32x4){0.f,0.f,0.f,0.f};

    for (int kt = 0; kt < K; kt += 64) {
#pragma unroll
        for (int i = 0; i < 4; ++i) {
            const unsigned short* gA = Xb + (size_t)(bm + srow[i]) * K + kt + scol[i]*8;
            __builtin_amdgcn_global_load_lds(
                (const __attribute__((address_space(1))) void*)gA,
                (__attribute__((address_space(3))) void*)&As[w*512 + i*2048], 16, 0, 0);
        }
#pragma unroll
        for (int i = 0; i < NLB; ++i) {
            const unsigned short* gB = Wb + (size_t)(bn + srow[i]) * K + kt + scol[i]*8;
            __builtin_amdgcn_global_load_lds(
                (const __attribute__((address_space(1))) void*)gB,
                (__attribute__((address_space(3))) void*)&Bs[w*512 + i*2048], 16, 0, 0);
        }
        __syncthreads();

#pragma unroll
        for (int ks = 0; ks < 2; ++ks) {
            const int c16 = (ks*4 + lg) ^ (l15 & 7);
            bf16x8 a[4], b[NT];
#pragma unroll
            for (int mt = 0; mt < 4; ++mt)
                a[mt] = *reinterpret_cast<const bf16x8*>(&As[(wr*64 + mt*16 + l15)*64 + c16*8]);
#pragma unroll
            for (int nt = 0; nt < NT; ++nt)
                b[nt] = *reinterpret_cast<const bf16x8*>(&Bs[(wc*(BN/2) + nt*16 + l15)*64 + c16*8]);
#pragma unroll
            for (int mt = 0; mt < 4; ++mt)
#pragma unroll
                for (int nt = 0; nt < NT; ++nt)
                    acc[mt][nt] = __builtin_amdgcn_mfma_f32_16x16x32_bf16(
                        a[mt], b[nt], acc[mt][nt], 0, 0, 0);
        }
        __syncthreads();
    }

    float bv[NT];
#pragma unroll
    for (int nt = 0; nt < NT; ++nt) bv[nt] = bias[bn + wc*(BN/2) + nt*16 + l15];

#pragma unroll
    for (int mt = 0; mt < 4; ++mt) {
#pragma unroll
        for (int nt = 0; nt < NT; ++nt) {
            const int n = bn + wc*(BN/2) + nt*16 + l15;
#pragma unroll
            for (int r = 0; r < 4; ++r) {
                const int m = bm + wr*64 + mt*16 + 4*lg + r;
                float v = acc[mt][nt][r] + bv[nt];
                if (DO_RELU) v = fmaxf(v, 0.f);
                if (RESID) v += resid[(size_t)m * N + n];
                if constexpr (VT) {
                    if (n < 1024)
                        ((unsigned short*)Yout)[(size_t)m * 1024 + n] = f2bf(v);
                    else
                        vtb[((size_t)(m >> 11) * 512 + (n - 1024)) * 2048 + (m & 2047)] = f2bf(v);
                } else if constexpr (BF16OUT) {
                    ((unsigned short*)Yout)[(size_t)m * N + n] = f2bf(v);
                } else {
                    ((float*)Yout)[(size_t)m * N + n] = v;
                }
            }
        }
    }
}

// ---------------- MFMA bf16 causal flash attention, unfolded ---------------
// Grid (bh=32, qb=32): 1024 blocks = 4 blocks/CU resident (27.6 KB LDS,
// launch_bounds(256,4) caps VGPR at 128) -> 16 waves/CU vs folded's 8.
// qb on the SLOW axis: each CU's 4 blocks get qb spread {q,q+8,q+16,q+24}
// -> per-CU work 52..80 tile-units (vs uniform 68), mild imbalance.
// Per-block body = round-12 first-validation-proven single-qb flash
// (KVBLK=64, global V^T, verified P/K/V swizzles), normalized ob write.
__global__ __launch_bounds__(256, 4) void attn_mfma_kernel(
    const unsigned short* __restrict__ qkvb, const unsigned short* __restrict__ vtb,
    unsigned short* __restrict__ ob)
{
    __shared__ unsigned short Ks[64*72];
    __shared__ unsigned short Vt[64*72];
    __shared__ unsigned short Plds[4*16*72];

    const int t    = threadIdx.x;
    const int lane = t & 63;
    const int w    = t >> 6;
    const int bh   = blockIdx.x;          // 0..31
    const int qb   = blockIdx.y;          // 0..31
    const int h    = bh & 7;
    const int b    = bh >> 3;
    const int q0w  = qb * 64 + w * 16;

    const unsigned short* base = qkvb + (size_t)b * S_ * 1024;
    const int l15 = lane & 15, lg = lane >> 4;
    const int skey = t >> 2;              // staging row 0..63 (K key / V d-row)
    const int sdk  = (t & 3) * 16;        // chunk
    const unsigned short* vbase = vtb + ((size_t)b * 512 + h*64 + skey) * 2048;
    unsigned short* pw_base = Plds + w*16*72;
    const int pxor = ((l15 >> 3) & 1) << 1;

    bf16x8 kr0, kr1, vr0, vr1;
#define LOADREG(KT) { \
        const unsigned short* pk_ = base + (size_t)((KT) + skey) * 1024 + 512 + h*64 + sdk; \
        kr0 = *reinterpret_cast<const bf16x8*>(pk_);       \
        kr1 = *reinterpret_cast<const bf16x8*>(pk_ + 8);   \
        const unsigned short* pv_ = vbase + (KT) + sdk;    \
        vr0 = *reinterpret_cast<const bf16x8*>(pv_);       \
        vr1 = *reinterpret_cast<const bf16x8*>(pv_ + 8); }

    bf16x8 qf0, qf1;
    {
        const unsigned short* qr = base + (size_t)(q0w + l15) * 1024 + h*64 + lg*8;
        qf0 = *reinterpret_cast<const bf16x8*>(qr);
        qf1 = *reinterpret_cast<const bf16x8*>(qr + 32);
    }

    f32x4 oacc[4];
#pragma unroll
    for (int i = 0; i < 4; ++i) oacc[i] = (f32x4){0.f,0.f,0.f,0.f};
    float mrow[4] = {-INFINITY,-INFINITY,-INFINITY,-INFINITY};
    float lrow[4] = {0.f,0.f,0.f,0.f};

    const int ntiles = qb + 1;
    LOADREG(0);

    for (int tile = 0; tile < ntiles; ++tile) {
        const int kt = tile * 64;
        __syncthreads();
        *reinterpret_cast<bf16x8*>(&Ks[skey*72 + sdk])     = kr0;
        *reinterpret_cast<bf16x8*>(&Ks[skey*72 + sdk + 8]) = kr1;
        *reinterpret_cast<bf16x8*>(&Vt[skey*72 + sdk])     = vr0;
        *reinterpret_cast<bf16x8*>(&Vt[skey*72 + sdk + 8]) = vr1;
        __syncthreads();
        const int nkt = (tile + 1 < ntiles) ? (kt + 64) : 0;
        LOADREG(nkt);

        // ---- QK^T: S[16q x 64key] ----
        f32x4 sacc[4];
        __builtin_amdgcn_s_setprio(1);
#pragma unroll
        for (int kt16 = 0; kt16 < 4; ++kt16) {
            sacc[kt16] = (f32x4){0.f,0.f,0.f,0.f};
            const unsigned short* kp = &Ks[(kt16*16 + l15)*72 + lg*8];
            bf16x8 k0 = *reinterpret_cast<const bf16x8*>(kp);
            bf16x8 k1 = *reinterpret_cast<const bf16x8*>(kp + 32);
            sacc[kt16] = __builtin_amdgcn_mfma_f32_16x16x32_bf16(qf0, k0, sacc[kt16], 0, 0, 0);
            sacc[kt16] = __builtin_amdgcn_mfma_f32_16x16x32_bf16(qf1, k1, sacc[kt16], 0, 0, 0);
        }
        __builtin_amdgcn_s_setprio(0);

        // ---- scale + causal mask ----
        const bool diag = (tile == ntiles - 1);
#pragma unroll
        for (int kt16 = 0; kt16 < 4; ++kt16) {
#pragma unroll
            for (int r = 0; r < 4; ++r) {
                float sv = sacc[kt16][r] * 0.125f;
                if (diag) {
                    const int key = kt + kt16*16 + l15;
                    const int q   = q0w + 4*lg + r;
                    if (key > q) sv = -INFINITY;
                }
                sacc[kt16][r] = sv;
            }
        }
        // ---- online softmax over 64 keys ----
#pragma unroll
        for (int r = 0; r < 4; ++r) {
            float tm = fmaxf(fmaxf(sacc[0][r], sacc[1][r]), fmaxf(sacc[2][r], sacc[3][r]));
#pragma unroll
            for (int off = 8; off; off >>= 1) tm = fmaxf(tm, __shfl_xor(tm, off, 64));
            const float nm = fmaxf(mrow[r], tm);
            const float al = __expf(mrow[r] - nm);
            mrow[r] = nm;
            float ps = 0.f;
            const int prow = (4*lg + r)*72;
            const int cswz = ((lg & 2) << 3);
#pragma unroll
            for (int kt16 = 0; kt16 < 4; ++kt16) {
                const float p = __expf(sacc[kt16][r] - nm);
                ps += p;
                pw_base[prow + ((kt16*16 + l15) ^ cswz)] = f2bf(p);
            }
#pragma unroll
            for (int off = 8; off; off >>= 1) ps += __shfl_xor(ps, off, 64);
            lrow[r] = lrow[r]*al + ps;
#pragma unroll
            for (int dt = 0; dt < 4; ++dt) oacc[dt][r] *= al;
        }

        // ---- PV: O[16q x 64d] += P @ V ----
        const unsigned short* pr = &pw_base[l15*72];
        bf16x8 pa0 = *reinterpret_cast<const bf16x8*>(&pr[((0 + lg) ^ pxor)*8]);
        bf16x8 pa1 = *reinterpret_cast<const bf16x8*>(&pr[((4 + lg) ^ pxor)*8]);
        __builtin_amdgcn_s_setprio(1);
#pragma unroll
        for (int dt = 0; dt < 4; ++dt) {
            const unsigned short* vrow = &Vt[(dt*16 + l15)*72];
            bf16x8 v0 = *reinterpret_cast<const bf16x8*>(&vrow[(0 + lg)*8]);
            bf16x8 v1 = *reinterpret_cast<const bf16x8*>(&vrow[(4 + lg)*8]);
            oacc[dt] = __builtin_amdgcn_mfma_f32_16x16x32_bf16(pa0, v0, oacc[dt], 0, 0, 0);
            oacc[dt] = __builtin_amdgcn_mfma_f32_16x16x32_bf16(pa1, v1, oacc[dt], 0, 0, 0);
        }
        __builtin_amdgcn_s_setprio(0);
    }

    // ---- normalized epilogue ----
#pragma unroll
    for (int dt = 0; dt < 4; ++dt) {
#pragma unroll
        for (int r = 0; r < 4; ++r) {
            const int q = q0w + 4*lg + r;
            ob[((size_t)b*S_ + q)*D_ + h*64 + dt*16 + l15] = f2bf(oacc[dt][r] / lrow[r]);
        }
    }
#undef LOADREG
}

// ---------------- LayerNorm (residual add, nullable outputs) ---------------
__global__ __launch_bounds__(256) void ln_kernel(
    float* __restrict__ dst, unsigned short* __restrict__ dst2,
    const float* __restrict__ src, const float* __restrict__ add,
    const float* __restrict__ w, const float* __restrict__ b, float eps)
{
    const int row = blockIdx.x, tid = threadIdx.x;
    const int lane = tid & 63, wave = tid >> 6;
    float2 v = *reinterpret_cast<const float2*>(src + (size_t)row * D_ + tid*2);
    if (add) {
        float2 a = *reinterpret_cast<const float2*>(add + (size_t)row * D_ + tid*2);
        v.x += a.x; v.y += a.y;
    }
    __shared__ float red[8];
    float s = v.x + v.y;
#pragma unroll
    for (int off = 32; off; off >>= 1) s += __shfl_xor(s, off, 64);
    if (lane == 0) red[wave] = s;
    __syncthreads();
    const float mean = (red[0]+red[1]+red[2]+red[3]) * (1.f/D_);
    const float d0 = v.x - mean, d1 = v.y - mean;
    float sq = d0*d0 + d1*d1;
#pragma unroll
    for (int off = 32; off; off >>= 1) sq += __shfl_xor(sq, off, 64);
    if (lane == 0) red[4+wave] = sq;
    __syncthreads();
    const float var = (red[4]+red[5]+red[6]+red[7]) * (1.f/D_);
    const float inv = rsqrtf(var + eps);
    const float o0 = d0*inv*w[tid*2] + b[tid*2];
    const float o1 = d1*inv*w[tid*2+1] + b[tid*2+1];
    if (dst)
        *reinterpret_cast<float2*>(dst + (size_t)row * D_ + tid*2) = make_float2(o0, o1);
    if (dst2) {
        ushort2 u; u.x = f2bf(o0); u.y = f2bf(o1);
        *reinterpret_cast<ushort2*>(dst2 + (size_t)row * D_ + tid*2) = u;
    }
}

// ---------------- dual LayerNorm: one read of x -> final out (f32) + kvn (bf16)
// Both use eps=1e-6 and the same mean/var of x; only (w,b) differ.
__global__ __launch_bounds__(256) void ln_dual_kernel(
    float* __restrict__ out, unsigned short* __restrict__ kvnb,
    const float* __restrict__ src,
    const float* __restrict__ nw, const float* __restrict__ nb,
    const float* __restrict__ cw, const float* __restrict__ cb)
{
    const int row = blockIdx.x, tid = threadIdx.x;
    const int lane = tid & 63, wave = tid >> 6;
    float2 v = *reinterpret_cast<const float2*>(src + (size_t)row * D_ + tid*2);
    __shared__ float red[8];
    float s = v.x + v.y;
#pragma unroll
    for (int off = 32; off; off >>= 1) s += __shfl_xor(s, off, 64);
    if (lane == 0) red[wave] = s;
    __syncthreads();
    const float mean = (red[0]+red[1]+red[2]+red[3]) * (1.f/D_);
    const float d0 = v.x - mean, d1 = v.y - mean;
    float sq = d0*d0 + d1*d1;
#pragma unroll
    for (int off = 32; off; off >>= 1) sq += __shfl_xor(sq, off, 64);
    if (lane == 0) red[4+wave] = sq;
    __syncthreads();
    const float var = (red[4]+red[5]+red[6]+red[7]) * (1.f/D_);
    const float inv = rsqrtf(var + 1e-6f);
    const float n0 = d0*inv;
    const float n1 = d1*inv;
    *reinterpret_cast<float2*>(out + (size_t)row * D_ + tid*2) =
        make_float2(n0*nw[tid*2] + nb[tid*2], n1*nw[tid*2+1] + nb[tid*2+1]);
    ushort2 u;
    u.x = f2bf(n0*cw[tid*2]   + cb[tid*2]);
    u.y = f2bf(n1*cw[tid*2+1] + cb[tid*2+1]);
    *reinterpret_cast<ushort2*>(kvnb + (size_t)row * D_ + tid*2) = u;
}

// ---------------- fused patch-CA tail ----------------
__global__ __launch_bounds__(256) void patch_tail_kernel(
    const float* __restrict__ x, const float* __restrict__ kvf,
    const float* __restrict__ ca_qkv_w, const float* __restrict__ ca_qkv_b,
    const float* __restrict__ ca_out_w, const float* __restrict__ ca_out_b,
    const float* __restrict__ ca_ln_w, const float* __restrict__ ca_ln_b,
    const float* __restrict__ norm_w, const float* __restrict__ norm_b,
    float* __restrict__ out)
{
    __shared__ float query[512];
    __shared__ float qs[512];
    __shared__ float ps[8*128];
    __shared__ float os[512];
    __shared__ float red[64];
    __shared__ float mred[8], sred[8];

    const int t  = threadIdx.x;
    const int bp = blockIdx.x;
    const int d0 = t * 2;
    const int lane = t & 63, wave = t >> 6;

    {
        const float* base = x + (size_t)bp * PLEN_ * D_ + d0;
        float s0 = 0.f, s1 = 0.f;
        for (int l = 0; l < PLEN_; ++l) {
            float2 v = *reinterpret_cast<const float2*>(base + (size_t)l * D_);
            s0 += v.x; s1 += v.y;
        }
        query[d0] = s0 * (1.f/PLEN_);
        query[d0+1] = s1 * (1.f/PLEN_);
    }
    __syncthreads();

    float qv0 = query[d0], qv1 = query[d0+1];
    {
        float s = qv0 + qv1;
#pragma unroll
        for (int off = 32; off; off >>= 1) s += __shfl_xor(s, off, 64);
        if (lane == 0) red[wave] = s;
        __syncthreads();
        const float mean = (red[0]+red[1]+red[2]+red[3]) * (1.f/D_);
        const float e0 = qv0 - mean, e1 = qv1 - mean;
        float sq = e0*e0 + e1*e1;
#pragma unroll
        for (int off = 32; off; off >>= 1) sq += __shfl_xor(sq, off, 64);
        if (lane == 0) red[4+wave] = sq;
        __syncthreads();
        const float var = (red[4]+red[5]+red[6]+red[7]) * (1.f/D_);
        const float inv = rsqrtf(var + 1e-6f);
        qs[d0]   = e0*inv*ca_ln_w[d0]   + ca_ln_b[d0];
        qs[d0+1] = e1*inv*ca_ln_w[d0+1] + ca_ln_b[d0+1];
    }
    __syncthreads();

    float qp0, qp1;
    {
        const float* w0 = ca_qkv_w + (size_t)d0 * D_;
        float a0 = ca_qkv_b[d0], a1 = ca_qkv_b[d0+1];
        for (int e = 0; e < D_; e += 4) {
            const float4 qn4 = *reinterpret_cast<const float4*>(&qs[e]);
            const float4 wa = *reinterpret_cast<const float4*>(w0 + e);
            const float4 wb = *reinterpret_cast<const float4*>(w0 + D_ + e);
            a0 += qn4.x*wa.x + qn4.y*wa.y + qn4.z*wa.z + qn4.w*wa.w;
            a1 += qn4.x*wb.x + qn4.y*wb.y + qn4.z*wb.z + qn4.w*wb.w;
        }
        qp0 = a0 * 0.125f; qp1 = a1 * 0.125f;
    }
    __syncthreads();
    qs[d0] = qp0; qs[d0+1] = qp1;
    __syncthreads();

    {
        const int h = t >> 5, c = t & 31;
        const float* qh = &qs[h*64];
#pragma unroll
        for (int j = 0; j < 4; ++j) {
            const int l = c*4 + j;
            const float* krow = kvf + ((size_t)bp*PLEN_ + l)*1024 + h*64;
            float acc = 0.f;
            for (int e = 0; e < 64; e += 4) {
                const float4 qe = *reinterpret_cast<const float4*>(qh + e);
                const float4 ke = *reinterpret_cast<const float4*>(krow + e);
                acc += qe.x*ke.x + qe.y*ke.y + qe.z*ke.z + qe.w*ke.w;
            }
            ps[h*128 + l] = acc;
        }
    }
    __syncthreads();

    {
        const int h = t >> 5, c = t & 31;
        float m4 = fmaxf(fmaxf(ps[h*128+c*4], ps[h*128+c*4+1]),
                         fmaxf(ps[h*128+c*4+2], ps[h*128+c*4+3]));
        red[h*8 + (c>>2)] = 0.f;
        __syncthreads();
        float mt_ = m4;
#pragma unroll
        for (int off = 1; off < 4; off <<= 1) mt_ = fmaxf(mt_, __shfl_xor(mt_, off, 64));
        if ((c & 3) == 0) red[h*8 + (c>>2)] = mt_;
        __syncthreads();
        if (t < 8) {
            float m = red[t*8];
#pragma unroll
            for (int j = 1; j < 8; ++j) m = fmaxf(m, red[t*8+j]);
            mred[t] = m;
        }
        __syncthreads();
        const float mh = mred[h];
        float ssum = 0.f;
#pragma unroll
        for (int j = 0; j < 4; ++j) {
            const float p = __expf(ps[h*128 + c*4 + j] - mh);
            ps[h*128 + c*4 + j] = p;
            ssum += p;
        }
#pragma unroll
        for (int off = 1; off < 4; off <<= 1) ssum += __shfl_xor(ssum, off, 64);
        if ((c & 3) == 0) red[h*8 + (c>>2)] = ssum;
        __syncthreads();
        if (t < 8) {
            float s = 0.f;
#pragma unroll
            for (int j = 0; j < 8; ++j) s += red[t*8+j];
            sred[t] = 1.f / s;
        }
    }
    __syncthreads();

    {
        const int h = t >> 5;
        const float* vbase = kvf + (size_t)bp*PLEN_*1024 + 512 + d0;
        float a0 = 0.f, a1 = 0.f;
        const float* ph = &ps[h*128];
        for (int l = 0; l < PLEN_; ++l) {
            const float p = ph[l];
            const float2 vv = *reinterpret_cast<const float2*>(vbase + (size_t)l*1024);
            a0 += p * vv.x; a1 += p * vv.y;
        }
        os[d0]   = a0 * sred[h];
        os[d0+1] = a1 * sred[h];
    }
    __syncthreads();

    float r0, r1;
    {
        const float* w0 = ca_out_w + (size_t)d0 * D_;
        float a0 = ca_out_b[d0], a1 = ca_out_b[d0+1];
        for (int e = 0; e < D_; e += 4) {
            const float4 oe = *reinterpret_cast<const float4*>(&os[e]);
            const float4 wa = *reinterpret_cast<const float4*>(w0 + e);
            const float4 wb = *reinterpret_cast<const float4*>(w0 + D_ + e);
            a0 += oe.x*wa.x + oe.y*wa.y + oe.z*wa.z + oe.w*wa.w;
            a1 += oe.x*wb.x + oe.y*wb.y + oe.z*wb.z + oe.w*wb.w;
        }
        r0 = query[d0] + a0;
        r1 = query[d0+1] + a1;
    }
    {
        float s = r0 + r1;
#pragma unroll
        for (int off = 32; off; off >>= 1) s += __shfl_xor(s, off, 64);
        __syncthreads();
        if (lane == 0) red[wave] = s;
        __syncthreads();
        const float mean = (red[0]+red[1]+red[2]+red[3]) * (1.f/D_);
        const float e0 = r0 - mean, e1 = r1 - mean;
        float sq = e0*e0 + e1*e1;
#pragma unroll
        for (int off = 32; off; off >>= 1) sq += __shfl_xor(sq, off, 64);
        if (lane == 0) red[4+wave] = sq;
        __syncthreads();
        const float var = (red[4]+red[5]+red[6]+red[7]) * (1.f/D_);
        const float inv = rsqrtf(var + 1e-6f);
        float* orow = out + ((size_t)(B_*S_) + bp) * D_;
        orow[d0]   = e0*inv*norm_w[d0]   + norm_b[d0];
        orow[d0+1] = e1*inv*norm_w[d0+1] + norm_b[d0+1];
    }
}

extern "C" void kernel_launch(void* const* d_in, const int* in_sizes, int n_in,
                              void* d_out, int out_size, void* d_ws, size_t ws_size,
                              hipStream_t stream)
{
    const int*   byte_seq = (const int*)d_in[0];
    const float* byte_emb = (const float*)d_in[2];
    const float* ng_emb   = (const float*)d_in[3];
    const float* qkv_w = (const float*)d_in[4];
    const float* qkv_b = (const float*)d_in[5];
    const float* out_w = (const float*)d_in[6];
    const float* out_b = (const float*)d_in[7];
    const float* ln1_w = (const float*)d_in[8];
    const float* ln1_b = (const float*)d_in[9];
    const float* ln2_w = (const float*)d_in[10];
    const float* ln2_b = (const float*)d_in[11];
    const float* ff1_w = (const float*)d_in[12];
    const float* ff1_b = (const float*)d_in[13];
    const float* ff2_w = (const float*)d_in[14];
    const float* ff2_b = (const float*)d_in[15];
    const float* ca_qkv_w = (const float*)d_in[16];
    const float* ca_qkv_b = (const float*)d_in[17];
    const float* ca_out_w = (const float*)d_in[18];
    const float* ca_out_b = (const float*)d_in[19];
    const float* ca_ln_w  = (const float*)d_in[20];
    const float* ca_ln_b  = (const float*)d_in[21];
    const float* norm_w   = (const float*)d_in[22];
    const float* norm_b   = (const float*)d_in[23];
    float* out = (float*)d_out;

    char* ws = (char*)d_ws;
    const size_t MB = 1024*1024;
    float*          x     = (float*)(ws);                    // [0,16M)
    char*           bufA  = ws + 16*MB;                      // [16,48M) qkvb/ff1b/kvf
    float*          bufB  = (float*)(ws + 48*MB);            // [48,64M) proj/ff2 f32
    unsigned short* vtb   = (unsigned short*)(ws + 48*MB);   // aliases bufB (disjoint lifetime)
    unsigned short* ob    = (unsigned short*)(ws + 64*MB);   // [64,72M)
    unsigned short* xb    = (unsigned short*)(ws + 72*MB);   // [72,80M)
    unsigned short* qkvw_b = (unsigned short*)(ws + 80*MB);
    unsigned short* outw_b = (unsigned short*)(ws + 83*MB);
    unsigned short* ff1w_b = (unsigned short*)(ws + 84*MB);
    unsigned short* ff2w_b = (unsigned short*)(ws + 88*MB);
    unsigned short* kvw_b  = (unsigned short*)(ws + 92*MB);

    unsigned short* qkvb = (unsigned short*)bufA;   // bf16 [8192][1024] ([q|k])
    unsigned short* ff1b = (unsigned short*)bufA;   // bf16 [8192][2048]
    float*          kvf  = (float*)bufA;            // f32  [8192][1024]

    const int M = B_ * S_;

    // 0. one-time weight casts to bf16 (single launch)
    cast5_kernel<<<(C0_+C1_+C2_+C3_+C4_+255)/256, 256, 0, stream>>>(
        qkv_w, out_w, ff1_w, ff2_w, ca_qkv_w + 512*512,
        qkvw_b, outw_b, ff1w_b, ff2w_b, kvw_b);

    // 1. byte embedding + n-gram hash adds
    embed_ngram_kernel<<<M, 128, 0, stream>>>(byte_seq, byte_emb, ng_emb, x, xb);

    // 2. transformer layers
    for (int l = 0; l < L_; ++l) {
        mgemm_kernel<0,1,128,1,0><<<dim3(1536/128, M/128), 256, 0, stream>>>(
            xb, qkvw_b + (size_t)l*1536*D_, qkv_b + l*1536, qkvb, vtb, nullptr, M, 1536, D_);
        attn_mfma_kernel<<<dim3(B_*H_, S_/64), 256, 0, stream>>>(qkvb, vtb, ob);
        mgemm_kernel<0,0,64,0,1><<<dim3(D_/64, M/128), 256, 0, stream>>>(
            ob, outw_b + (size_t)l*D_*D_, out_b + l*D_, bufB, nullptr, x, M, D_, D_);
        ln_kernel<<<M, 256, 0, stream>>>(x, xb, bufB, nullptr, ln1_w + l*D_, ln1_b + l*D_, 1e-5f);
        mgemm_kernel<1,1,128,0,0><<<dim3(2048/128, M/128), 256, 0, stream>>>(
            xb, ff1w_b + (size_t)l*2048*D_, ff1_b + l*2048, ff1b, nullptr, nullptr, M, 2048, D_);
        mgemm_kernel<0,0,64,0,1><<<dim3(D_/64, M/128), 256, 0, stream>>>(
            ff1b, ff2w_b + (size_t)l*D_*2048, ff2_b + l*D_, bufB, nullptr, x, M, D_, 2048);
        ln_kernel<<<M, 256, 0, stream>>>(x, xb, bufB, nullptr, ln2_w + l*D_, ln2_b + l*D_, 1e-5f);
    }

    // 3. dual LN (final out + kvn bf16, one pass) -> kv mgemm -> fused tail
    ln_dual_kernel<<<M, 256, 0, stream>>>(out, xb, x, norm_w, norm_b, ca_ln_w, ca_ln_b);
    mgemm_kernel<0,0,128,0,0><<<dim3(1024/128, M/128), 256, 0, stream>>>(
        xb, kvw_b, ca_qkv_b + 512, kvf, nullptr, nullptr, M, 1024, D_);
    patch_tail_kernel<<<B_*NPATCH_, 256, 0, stream>>>(
        x, kvf, ca_qkv_w, ca_qkv_b, ca_out_w, ca_out_b,
        ca_ln_w, ca_ln_b, norm_w, norm_b, out);
}

// Round 15
// 505.906 us; speedup vs baseline: 1.0816x; 1.0816x over previous
//
#include <hip/hip_runtime.h>
#include <hip/hip_bf16.h>

#define B_ 4
#define S_ 2048
#define D_ 512
#define H_ 8
#define HD_ 64
#define L_ 2
#define V_ 30000
#define NPATCH_ 16
#define PLEN_ 128

typedef short bf16x8 __attribute__((ext_vector_type(8)));
typedef float f32x4 __attribute__((ext_vector_type(4)));

__device__ __forceinline__ unsigned short f2bf(float f) {
    unsigned u = __float_as_uint(f);
    return (unsigned short)((u + 0x7FFFu + ((u >> 16) & 1u)) >> 16);   // RNE
}
__device__ __forceinline__ float bf2f(unsigned short u) {
    return __uint_as_float(((unsigned int)u) << 16);
}

// ---------------- merged f32 -> bf16 weight casts (1 launch) ----------------
#define C0_ (2*1536*512/4)
#define C1_ (2*512*512/4)
#define C2_ (2*2048*512/4)
#define C3_ (2*512*2048/4)
#define C4_ (1024*512/4)
__global__ __launch_bounds__(256) void cast5_kernel(
    const float* __restrict__ s0, const float* __restrict__ s1,
    const float* __restrict__ s2, const float* __restrict__ s3,
    const float* __restrict__ s4,
    unsigned short* __restrict__ d0, unsigned short* __restrict__ d1,
    unsigned short* __restrict__ d2, unsigned short* __restrict__ d3,
    unsigned short* __restrict__ d4)
{
    int i = blockIdx.x * 256 + threadIdx.x;
    const float* s; unsigned short* d;
    if      (i < C0_)                  { s = s0; d = d0; }
    else if ((i -= C0_) < C1_)         { s = s1; d = d1; }
    else if ((i -= C1_) < C2_)         { s = s2; d = d2; }
    else if ((i -= C2_) < C3_)         { s = s3; d = d3; }
    else if ((i -= C3_) < C4_)         { s = s4; d = d4; }
    else return;
    const float4 v = *reinterpret_cast<const float4*>(s + (size_t)i * 4);
    ushort4 o;
    o.x = f2bf(v.x); o.y = f2bf(v.y); o.z = f2bf(v.z); o.w = f2bf(v.w);
    *reinterpret_cast<ushort4*>(d + (size_t)i * 4) = o;
}

// ---------------- embed + n-gram hash add (f32 + bf16 shadow) -------------
__global__ __launch_bounds__(128) void embed_ngram_kernel(
    const int* __restrict__ bytes, const float* __restrict__ byte_emb,
    const float* __restrict__ ng_emb, float* __restrict__ x,
    unsigned short* __restrict__ xb)
{
    const int bs = blockIdx.x;
    const int s  = bs % S_;
    const int b  = bs / S_;
    const int d  = threadIdx.x * 4;
    const int* brow = bytes + (size_t)b * S_;

    const int c = brow[s];
    float4 v = *reinterpret_cast<const float4*>(byte_emb + (size_t)c * D_ + d);

    if (s >= 2) {
        int h = (brow[s-2]*961 + brow[s-1]*31 + brow[s]) % V_;
        const float4 g = *reinterpret_cast<const float4*>(ng_emb + ((size_t)0*V_ + h)*D_ + d);
        v.x += 0.25f*g.x; v.y += 0.25f*g.y; v.z += 0.25f*g.z; v.w += 0.25f*g.w;
    }
    if (s >= 3) {
        int h = (brow[s-3]*29791 + brow[s-2]*961 + brow[s-1]*31 + brow[s]) % V_;
        const float4 g = *reinterpret_cast<const float4*>(ng_emb + ((size_t)1*V_ + h)*D_ + d);
        v.x += 0.25f*g.x; v.y += 0.25f*g.y; v.z += 0.25f*g.z; v.w += 0.25f*g.w;
    }
    if (s >= 4) {
        int h = (brow[s-4]*23521 + brow[s-3]*29791 + brow[s-2]*961 + brow[s-1]*31 + brow[s]) % V_;
        const float4 g = *reinterpret_cast<const float4*>(ng_emb + ((size_t)2*V_ + h)*D_ + d);
        v.x += 0.25f*g.x; v.y += 0.25f*g.y; v.z += 0.25f*g.z; v.w += 0.25f*g.w;
    }
    *reinterpret_cast<float4*>(x + (size_t)bs * D_ + d) = v;
    ushort4 o;
    o.x = f2bf(v.x); o.y = f2bf(v.y); o.z = f2bf(v.z); o.w = f2bf(v.w);
    *reinterpret_cast<ushort4*>(xb + (size_t)bs * D_ + d) = o;
}

// ---------------- MFMA bf16 GEMM: Y = X @ W^T + bias [,relu][,+resid] ------
template<int DO_RELU, int BF16OUT, int BN, int VT, int RESID>
__global__ __launch_bounds__(256) void mgemm_kernel(
    const unsigned short* __restrict__ Xb, const unsigned short* __restrict__ Wb,
    const float* __restrict__ bias, void* __restrict__ Yout,
    unsigned short* __restrict__ vtb, const float* __restrict__ resid,
    int M, int N, int K)
{
    constexpr int NT  = BN / 32;
    constexpr int NLB = BN / 32;
    __shared__ unsigned short As[128*64];
    __shared__ unsigned short Bs[BN*64];

    const int t    = threadIdx.x;
    const int lane = t & 63;
    const int w    = t >> 6;

    const int nwg = gridDim.x * gridDim.y;
    const int bid = blockIdx.y * gridDim.x + blockIdx.x;
    const int swz = (bid & 7) * (nwg >> 3) + (bid >> 3);
    const int bx  = swz % gridDim.x, by = swz / gridDim.x;

    const int bm   = by * 128, bn = bx * BN;
    const int l15  = lane & 15, lg = lane >> 4;
    const int wr   = w >> 1, wc = w & 1;

    int srow[4], scol[4];
#pragma unroll
    for (int i = 0; i < 4; ++i) {
        const int off = w*1024 + i*4096 + lane*16;
        srow[i] = off >> 7;
        scol[i] = ((off >> 4) & 7) ^ (srow[i] & 7);
    }

    f32x4 acc[4][NT];
#pragma unroll
    for (int mt = 0; mt < 4; ++mt)
#pragma unroll
        for (int nt = 0; nt < NT; ++nt) acc[mt][nt] = (f32x4){0.f,0.f,0.f,0.f};

    for (int kt = 0; kt < K; kt += 64) {
#pragma unroll
        for (int i = 0; i < 4; ++i) {
            const unsigned short* gA = Xb + (size_t)(bm + srow[i]) * K + kt + scol[i]*8;
            __builtin_amdgcn_global_load_lds(
                (const __attribute__((address_space(1))) void*)gA,
                (__attribute__((address_space(3))) void*)&As[w*512 + i*2048], 16, 0, 0);
        }
#pragma unroll
        for (int i = 0; i < NLB; ++i) {
            const unsigned short* gB = Wb + (size_t)(bn + srow[i]) * K + kt + scol[i]*8;
            __builtin_amdgcn_global_load_lds(
                (const __attribute__((address_space(1))) void*)gB,
                (__attribute__((address_space(3))) void*)&Bs[w*512 + i*2048], 16, 0, 0);
        }
        __syncthreads();

#pragma unroll
        for (int ks = 0; ks < 2; ++ks) {
            const int c16 = (ks*4 + lg) ^ (l15 & 7);
            bf16x8 a[4], b[NT];
#pragma unroll
            for (int mt = 0; mt < 4; ++mt)
                a[mt] = *reinterpret_cast<const bf16x8*>(&As[(wr*64 + mt*16 + l15)*64 + c16*8]);
#pragma unroll
            for (int nt = 0; nt < NT; ++nt)
                b[nt] = *reinterpret_cast<const bf16x8*>(&Bs[(wc*(BN/2) + nt*16 + l15)*64 + c16*8]);
#pragma unroll
            for (int mt = 0; mt < 4; ++mt)
#pragma unroll
                for (int nt = 0; nt < NT; ++nt)
                    acc[mt][nt] = __builtin_amdgcn_mfma_f32_16x16x32_bf16(
                        a[mt], b[nt], acc[mt][nt], 0, 0, 0);
        }
        __syncthreads();
    }

    float bv[NT];
#pragma unroll
    for (int nt = 0; nt < NT; ++nt) bv[nt] = bias[bn + wc*(BN/2) + nt*16 + l15];

#pragma unroll
    for (int mt = 0; mt < 4; ++mt) {
#pragma unroll
        for (int nt = 0; nt < NT; ++nt) {
            const int n = bn + wc*(BN/2) + nt*16 + l15;
#pragma unroll
            for (int r = 0; r < 4; ++r) {
                const int m = bm + wr*64 + mt*16 + 4*lg + r;
                float v = acc[mt][nt][r] + bv[nt];
                if (DO_RELU) v = fmaxf(v, 0.f);
                if (RESID) v += resid[(size_t)m * N + n];
                if constexpr (VT) {
                    if (n < 1024)
                        ((unsigned short*)Yout)[(size_t)m * 1024 + n] = f2bf(v);
                    else
                        vtb[((size_t)(m >> 11) * 512 + (n - 1024)) * 2048 + (m & 2047)] = f2bf(v);
                } else if constexpr (BF16OUT) {
                    ((unsigned short*)Yout)[(size_t)m * N + n] = f2bf(v);
                } else {
                    ((float*)Yout)[(size_t)m * N + n] = v;
                }
            }
        }
    }
}

// ---------------- MFMA bf16 causal flash attention (round-13 proven) -------
// qkvb rows [q|k] stride 1024; vtb[b][d(512)][s(2048)] pre-transposed V.
// Folded triangle: pair {qp, 31-qp} = 17 tiles uniform; KVBLK=128.
__global__ __launch_bounds__(256) void attn_mfma_kernel(
    const unsigned short* __restrict__ qkvb, const unsigned short* __restrict__ vtb,
    unsigned short* __restrict__ ob)
{
    __shared__ unsigned short Ks[128*72];
    __shared__ unsigned short Vt[64*136];
    __shared__ unsigned short Plds[4*16*136];

    const int t    = threadIdx.x;
    const int lane = t & 63;
    const int w    = t >> 6;
    const int qp   = blockIdx.x;
    const int bh   = blockIdx.y;
    const int h    = bh & 7;
    const int b    = bh >> 3;

    const unsigned short* base = qkvb + (size_t)b * S_ * 1024;
    const int l15 = lane & 15, lg = lane >> 4;
    const int skey = t >> 1;              // K staging key 0..127
    const int sd0  = (t & 1) * 32;        // K staging d-range
    const int sdv  = t >> 2;              // V staging d-row 0..63
    const int skc  = (t & 3) * 32;        // V staging k-range
    const unsigned short* vbase = vtb + ((size_t)b * 512 + h*64 + sdv) * 2048;
    unsigned short* pw_base = Plds + w*16*136;
    const int pxor = ((l15 >> 3) & 1) << 1;   // P read chunk xor

    bf16x8 kr0, kr1, kr2, kr3, vr0, vr1, vr2, vr3;
#define LOADREG(KT) { \
        const unsigned short* pk_ = base + (size_t)((KT) + skey) * 1024 + 512 + h*64 + sd0; \
        kr0 = *reinterpret_cast<const bf16x8*>(pk_);       \
        kr1 = *reinterpret_cast<const bf16x8*>(pk_ + 8);   \
        kr2 = *reinterpret_cast<const bf16x8*>(pk_ + 16);  \
        kr3 = *reinterpret_cast<const bf16x8*>(pk_ + 24);  \
        const unsigned short* pv_ = vbase + (KT) + skc;    \
        vr0 = *reinterpret_cast<const bf16x8*>(pv_);       \
        vr1 = *reinterpret_cast<const bf16x8*>(pv_ + 8);   \
        vr2 = *reinterpret_cast<const bf16x8*>(pv_ + 16);  \
        vr3 = *reinterpret_cast<const bf16x8*>(pv_ + 24); }

    LOADREG(0);

#pragma unroll
    for (int half = 0; half < 2; ++half) {
        const int qb  = half ? (31 - qp) : qp;
        const int q0w = qb * 64 + w * 16;

        bf16x8 qf0, qf1;
        {
            const unsigned short* qr = base + (size_t)(q0w + l15) * 1024 + h*64 + lg*8;
            qf0 = *reinterpret_cast<const bf16x8*>(qr);
            qf1 = *reinterpret_cast<const bf16x8*>(qr + 32);
        }

        f32x4 oacc[4];
#pragma unroll
        for (int i = 0; i < 4; ++i) oacc[i] = (f32x4){0.f,0.f,0.f,0.f};
        float mrow[4] = {-INFINITY,-INFINITY,-INFINITY,-INFINITY};
        float lrow[4] = {0.f,0.f,0.f,0.f};

        const int ntiles = (qb + 2) >> 1;
        for (int tile = 0; tile < ntiles; ++tile) {
            const int kt = tile * 128;
            __syncthreads();
            *reinterpret_cast<bf16x8*>(&Ks[skey*72 + sd0])      = kr0;
            *reinterpret_cast<bf16x8*>(&Ks[skey*72 + sd0 + 8])  = kr1;
            *reinterpret_cast<bf16x8*>(&Ks[skey*72 + sd0 + 16]) = kr2;
            *reinterpret_cast<bf16x8*>(&Ks[skey*72 + sd0 + 24]) = kr3;
            *reinterpret_cast<bf16x8*>(&Vt[sdv*136 + skc])      = vr0;
            *reinterpret_cast<bf16x8*>(&Vt[sdv*136 + skc + 8])  = vr1;
            *reinterpret_cast<bf16x8*>(&Vt[sdv*136 + skc + 16]) = vr2;
            *reinterpret_cast<bf16x8*>(&Vt[sdv*136 + skc + 24]) = vr3;
            __syncthreads();
            const int nkt = (tile + 1 < ntiles) ? (kt + 128) : 0;
            LOADREG(nkt);

            f32x4 sacc[8];
            __builtin_amdgcn_s_setprio(1);
#pragma unroll
            for (int kt16 = 0; kt16 < 8; ++kt16) {
                sacc[kt16] = (f32x4){0.f,0.f,0.f,0.f};
                const unsigned short* kp = &Ks[(kt16*16 + l15)*72 + lg*8];
                bf16x8 k0 = *reinterpret_cast<const bf16x8*>(kp);
                bf16x8 k1 = *reinterpret_cast<const bf16x8*>(kp + 32);
                sacc[kt16] = __builtin_amdgcn_mfma_f32_16x16x32_bf16(qf0, k0, sacc[kt16], 0, 0, 0);
                sacc[kt16] = __builtin_amdgcn_mfma_f32_16x16x32_bf16(qf1, k1, sacc[kt16], 0, 0, 0);
            }
            __builtin_amdgcn_s_setprio(0);

            const bool diag = (tile == ntiles - 1);
#pragma unroll
            for (int kt16 = 0; kt16 < 8; ++kt16) {
#pragma unroll
                for (int r = 0; r < 4; ++r) {
                    float s = sacc[kt16][r] * 0.125f;
                    if (diag) {
                        const int key = kt + kt16*16 + l15;
                        const int q   = q0w + 4*lg + r;
                        if (key > q) s = -INFINITY;
                    }
                    sacc[kt16][r] = s;
                }
            }
#pragma unroll
            for (int r = 0; r < 4; ++r) {
                float tm = fmaxf(
                    fmaxf(fmaxf(sacc[0][r], sacc[1][r]), fmaxf(sacc[2][r], sacc[3][r])),
                    fmaxf(fmaxf(sacc[4][r], sacc[5][r]), fmaxf(sacc[6][r], sacc[7][r])));
#pragma unroll
                for (int off = 8; off; off >>= 1) tm = fmaxf(tm, __shfl_xor(tm, off, 64));
                const float nm = fmaxf(mrow[r], tm);
                const float al = __expf(mrow[r] - nm);
                mrow[r] = nm;
                float ps = 0.f;
                const int prow = (4*lg + r)*136;
                const int cswz = ((lg & 2) << 3);
#pragma unroll
                for (int kt16 = 0; kt16 < 8; ++kt16) {
                    const float p = __expf(sacc[kt16][r] - nm);
                    ps += p;
                    pw_base[prow + ((kt16*16 + l15) ^ cswz)] = f2bf(p);
                }
#pragma unroll
                for (int off = 8; off; off >>= 1) ps += __shfl_xor(ps, off, 64);
                lrow[r] = lrow[r]*al + ps;
#pragma unroll
                for (int dt = 0; dt < 4; ++dt) oacc[dt][r] *= al;
            }

            const unsigned short* pr = &pw_base[l15*136];
            bf16x8 pa0 = *reinterpret_cast<const bf16x8*>(&pr[(( 0 + lg) ^ pxor)*8]);
            bf16x8 pa1 = *reinterpret_cast<const bf16x8*>(&pr[(( 4 + lg) ^ pxor)*8]);
            bf16x8 pa2 = *reinterpret_cast<const bf16x8*>(&pr[(( 8 + lg) ^ pxor)*8]);
            bf16x8 pa3 = *reinterpret_cast<const bf16x8*>(&pr[((12 + lg) ^ pxor)*8]);
            __builtin_amdgcn_s_setprio(1);
#pragma unroll
            for (int dt = 0; dt < 4; ++dt) {
                const unsigned short* vrow = &Vt[(dt*16 + l15)*136];
                bf16x8 v0 = *reinterpret_cast<const bf16x8*>(&vrow[( 0 + lg)*8]);
                bf16x8 v1 = *reinterpret_cast<const bf16x8*>(&vrow[( 4 + lg)*8]);
                bf16x8 v2 = *reinterpret_cast<const bf16x8*>(&vrow[( 8 + lg)*8]);
                bf16x8 v3 = *reinterpret_cast<const bf16x8*>(&vrow[(12 + lg)*8]);
                oacc[dt] = __builtin_amdgcn_mfma_f32_16x16x32_bf16(pa0, v0, oacc[dt], 0, 0, 0);
                oacc[dt] = __builtin_amdgcn_mfma_f32_16x16x32_bf16(pa1, v1, oacc[dt], 0, 0, 0);
                oacc[dt] = __builtin_amdgcn_mfma_f32_16x16x32_bf16(pa2, v2, oacc[dt], 0, 0, 0);
                oacc[dt] = __builtin_amdgcn_mfma_f32_16x16x32_bf16(pa3, v3, oacc[dt], 0, 0, 0);
            }
            __builtin_amdgcn_s_setprio(0);
        }

#pragma unroll
        for (int dt = 0; dt < 4; ++dt) {
#pragma unroll
            for (int r = 0; r < 4; ++r) {
                const int q = q0w + 4*lg + r;
                ob[((size_t)b*S_ + q)*D_ + h*64 + dt*16 + l15] = f2bf(oacc[dt][r] / lrow[r]);
            }
        }
    }
#undef LOADREG
}

// ---------------- LayerNorm (residual add, nullable outputs) ---------------
__global__ __launch_bounds__(256) void ln_kernel(
    float* __restrict__ dst, unsigned short* __restrict__ dst2,
    const float* __restrict__ src, const float* __restrict__ add,
    const float* __restrict__ w, const float* __restrict__ b, float eps)
{
    const int row = blockIdx.x, tid = threadIdx.x;
    const int lane = tid & 63, wave = tid >> 6;
    float2 v = *reinterpret_cast<const float2*>(src + (size_t)row * D_ + tid*2);
    if (add) {
        float2 a = *reinterpret_cast<const float2*>(add + (size_t)row * D_ + tid*2);
        v.x += a.x; v.y += a.y;
    }
    __shared__ float red[8];
    float s = v.x + v.y;
#pragma unroll
    for (int off = 32; off; off >>= 1) s += __shfl_xor(s, off, 64);
    if (lane == 0) red[wave] = s;
    __syncthreads();
    const float mean = (red[0]+red[1]+red[2]+red[3]) * (1.f/D_);
    const float d0 = v.x - mean, d1 = v.y - mean;
    float sq = d0*d0 + d1*d1;
#pragma unroll
    for (int off = 32; off; off >>= 1) sq += __shfl_xor(sq, off, 64);
    if (lane == 0) red[4+wave] = sq;
    __syncthreads();
    const float var = (red[4]+red[5]+red[6]+red[7]) * (1.f/D_);
    const float inv = rsqrtf(var + eps);
    const float o0 = d0*inv*w[tid*2] + b[tid*2];
    const float o1 = d1*inv*w[tid*2+1] + b[tid*2+1];
    if (dst)
        *reinterpret_cast<float2*>(dst + (size_t)row * D_ + tid*2) = make_float2(o0, o1);
    if (dst2) {
        ushort2 u; u.x = f2bf(o0); u.y = f2bf(o1);
        *reinterpret_cast<ushort2*>(dst2 + (size_t)row * D_ + tid*2) = u;
    }
}

// ---------------- dual LayerNorm: one read of x -> final out (f32) + kvn (bf16)
__global__ __launch_bounds__(256) void ln_dual_kernel(
    float* __restrict__ out, unsigned short* __restrict__ kvnb,
    const float* __restrict__ src,
    const float* __restrict__ nw, const float* __restrict__ nb,
    const float* __restrict__ cw, const float* __restrict__ cb)
{
    const int row = blockIdx.x, tid = threadIdx.x;
    const int lane = tid & 63, wave = tid >> 6;
    float2 v = *reinterpret_cast<const float2*>(src + (size_t)row * D_ + tid*2);
    __shared__ float red[8];
    float s = v.x + v.y;
#pragma unroll
    for (int off = 32; off; off >>= 1) s += __shfl_xor(s, off, 64);
    if (lane == 0) red[wave] = s;
    __syncthreads();
    const float mean = (red[0]+red[1]+red[2]+red[3]) * (1.f/D_);
    const float d0 = v.x - mean, d1 = v.y - mean;
    float sq = d0*d0 + d1*d1;
#pragma unroll
    for (int off = 32; off; off >>= 1) sq += __shfl_xor(sq, off, 64);
    if (lane == 0) red[4+wave] = sq;
    __syncthreads();
    const float var = (red[4]+red[5]+red[6]+red[7]) * (1.f/D_);
    const float inv = rsqrtf(var + 1e-6f);
    const float n0 = d0*inv;
    const float n1 = d1*inv;
    *reinterpret_cast<float2*>(out + (size_t)row * D_ + tid*2) =
        make_float2(n0*nw[tid*2] + nb[tid*2], n1*nw[tid*2+1] + nb[tid*2+1]);
    ushort2 u;
    u.x = f2bf(n0*cw[tid*2]   + cb[tid*2]);
    u.y = f2bf(n1*cw[tid*2+1] + cb[tid*2+1]);
    *reinterpret_cast<ushort2*>(kvnb + (size_t)row * D_ + tid*2) = u;
}

// ---------------- fused patch-CA tail ----------------
__global__ __launch_bounds__(256) void patch_tail_kernel(
    const float* __restrict__ x, const float* __restrict__ kvf,
    const float* __restrict__ ca_qkv_w, const float* __restrict__ ca_qkv_b,
    const float* __restrict__ ca_out_w, const float* __restrict__ ca_out_b,
    const float* __restrict__ ca_ln_w, const float* __restrict__ ca_ln_b,
    const float* __restrict__ norm_w, const float* __restrict__ norm_b,
    float* __restrict__ out)
{
    __shared__ float query[512];
    __shared__ float qs[512];
    __shared__ float ps[8*128];
    __shared__ float os[512];
    __shared__ float red[64];
    __shared__ float mred[8], sred[8];

    const int t  = threadIdx.x;
    const int bp = blockIdx.x;
    const int d0 = t * 2;
    const int lane = t & 63, wave = t >> 6;

    {
        const float* base = x + (size_t)bp * PLEN_ * D_ + d0;
        float s0 = 0.f, s1 = 0.f;
        for (int l = 0; l < PLEN_; ++l) {
            float2 v = *reinterpret_cast<const float2*>(base + (size_t)l * D_);
            s0 += v.x; s1 += v.y;
        }
        query[d0] = s0 * (1.f/PLEN_);
        query[d0+1] = s1 * (1.f/PLEN_);
    }
    __syncthreads();

    float qv0 = query[d0], qv1 = query[d0+1];
    {
        float s = qv0 + qv1;
#pragma unroll
        for (int off = 32; off; off >>= 1) s += __shfl_xor(s, off, 64);
        if (lane == 0) red[wave] = s;
        __syncthreads();
        const float mean = (red[0]+red[1]+red[2]+red[3]) * (1.f/D_);
        const float e0 = qv0 - mean, e1 = qv1 - mean;
        float sq = e0*e0 + e1*e1;
#pragma unroll
        for (int off = 32; off; off >>= 1) sq += __shfl_xor(sq, off, 64);
        if (lane == 0) red[4+wave] = sq;
        __syncthreads();
        const float var = (red[4]+red[5]+red[6]+red[7]) * (1.f/D_);
        const float inv = rsqrtf(var + 1e-6f);
        qs[d0]   = e0*inv*ca_ln_w[d0]   + ca_ln_b[d0];
        qs[d0+1] = e1*inv*ca_ln_w[d0+1] + ca_ln_b[d0+1];
    }
    __syncthreads();

    float qp0, qp1;
    {
        const float* w0 = ca_qkv_w + (size_t)d0 * D_;
        float a0 = ca_qkv_b[d0], a1 = ca_qkv_b[d0+1];
        for (int e = 0; e < D_; e += 4) {
            const float4 qn4 = *reinterpret_cast<const float4*>(&qs[e]);
            const float4 wa = *reinterpret_cast<const float4*>(w0 + e);
            const float4 wb = *reinterpret_cast<const float4*>(w0 + D_ + e);
            a0 += qn4.x*wa.x + qn4.y*wa.y + qn4.z*wa.z + qn4.w*wa.w;
            a1 += qn4.x*wb.x + qn4.y*wb.y + qn4.z*wb.z + qn4.w*wb.w;
        }
        qp0 = a0 * 0.125f; qp1 = a1 * 0.125f;
    }
    __syncthreads();
    qs[d0] = qp0; qs[d0+1] = qp1;
    __syncthreads();

    {
        const int h = t >> 5, c = t & 31;
        const float* qh = &qs[h*64];
#pragma unroll
        for (int j = 0; j < 4; ++j) {
            const int l = c*4 + j;
            const float* krow = kvf + ((size_t)bp*PLEN_ + l)*1024 + h*64;
            float acc = 0.f;
            for (int e = 0; e < 64; e += 4) {
                const float4 qe = *reinterpret_cast<const float4*>(qh + e);
                const float4 ke = *reinterpret_cast<const float4*>(krow + e);
                acc += qe.x*ke.x + qe.y*ke.y + qe.z*ke.z + qe.w*ke.w;
            }
            ps[h*128 + l] = acc;
        }
    }
    __syncthreads();

    {
        const int h = t >> 5, c = t & 31;
        float m4 = fmaxf(fmaxf(ps[h*128+c*4], ps[h*128+c*4+1]),
                         fmaxf(ps[h*128+c*4+2], ps[h*128+c*4+3]));
        red[h*8 + (c>>2)] = 0.f;
        __syncthreads();
        float mt_ = m4;
#pragma unroll
        for (int off = 1; off < 4; off <<= 1) mt_ = fmaxf(mt_, __shfl_xor(mt_, off, 64));
        if ((c & 3) == 0) red[h*8 + (c>>2)] = mt_;
        __syncthreads();
        if (t < 8) {
            float m = red[t*8];
#pragma unroll
            for (int j = 1; j < 8; ++j) m = fmaxf(m, red[t*8+j]);
            mred[t] = m;
        }
        __syncthreads();
        const float mh = mred[h];
        float ssum = 0.f;
#pragma unroll
        for (int j = 0; j < 4; ++j) {
            const float p = __expf(ps[h*128 + c*4 + j] - mh);
            ps[h*128 + c*4 + j] = p;
            ssum += p;
        }
#pragma unroll
        for (int off = 1; off < 4; off <<= 1) ssum += __shfl_xor(ssum, off, 64);
        if ((c & 3) == 0) red[h*8 + (c>>2)] = ssum;
        __syncthreads();
        if (t < 8) {
            float s = 0.f;
#pragma unroll
            for (int j = 0; j < 8; ++j) s += red[t*8+j];
            sred[t] = 1.f / s;
        }
    }
    __syncthreads();

    {
        const int h = t >> 5;
        const float* vbase = kvf + (size_t)bp*PLEN_*1024 + 512 + d0;
        float a0 = 0.f, a1 = 0.f;
        const float* ph = &ps[h*128];
        for (int l = 0; l < PLEN_; ++l) {
            const float p = ph[l];
            const float2 vv = *reinterpret_cast<const float2*>(vbase + (size_t)l*1024);
            a0 += p * vv.x; a1 += p * vv.y;
        }
        os[d0]   = a0 * sred[h];
        os[d0+1] = a1 * sred[h];
    }
    __syncthreads();

    float r0, r1;
    {
        const float* w0 = ca_out_w + (size_t)d0 * D_;
        float a0 = ca_out_b[d0], a1 = ca_out_b[d0+1];
        for (int e = 0; e < D_; e += 4) {
            const float4 oe = *reinterpret_cast<const float4*>(&os[e]);
            const float4 wa = *reinterpret_cast<const float4*>(w0 + e);
            const float4 wb = *reinterpret_cast<const float4*>(w0 + D_ + e);
            a0 += oe.x*wa.x + oe.y*wa.y + oe.z*wa.z + oe.w*wa.w;
            a1 += oe.x*wb.x + oe.y*wb.y + oe.z*wb.z + oe.w*wb.w;
        }
        r0 = query[d0] + a0;
        r1 = query[d0+1] + a1;
    }
    {
        float s = r0 + r1;
#pragma unroll
        for (int off = 32; off; off >>= 1) s += __shfl_xor(s, off, 64);
        __syncthreads();
        if (lane == 0) red[wave] = s;
        __syncthreads();
        const float mean = (red[0]+red[1]+red[2]+red[3]) * (1.f/D_);
        const float e0 = r0 - mean, e1 = r1 - mean;
        float sq = e0*e0 + e1*e1;
#pragma unroll
        for (int off = 32; off; off >>= 1) sq += __shfl_xor(sq, off, 64);
        if (lane == 0) red[4+wave] = sq;
        __syncthreads();
        const float var = (red[4]+red[5]+red[6]+red[7]) * (1.f/D_);
        const float inv = rsqrtf(var + 1e-6f);
        float* orow = out + ((size_t)(B_*S_) + bp) * D_;
        orow[d0]   = e0*inv*norm_w[d0]   + norm_b[d0];
        orow[d0+1] = e1*inv*norm_w[d0+1] + norm_b[d0+1];
    }
}

extern "C" void kernel_launch(void* const* d_in, const int* in_sizes, int n_in,
                              void* d_out, int out_size, void* d_ws, size_t ws_size,
                              hipStream_t stream)
{
    const int*   byte_seq = (const int*)d_in[0];
    const float* byte_emb = (const float*)d_in[2];
    const float* ng_emb   = (const float*)d_in[3];
    const float* qkv_w = (const float*)d_in[4];
    const float* qkv_b = (const float*)d_in[5];
    const float* out_w = (const float*)d_in[6];
    const float* out_b = (const float*)d_in[7];
    const float* ln1_w = (const float*)d_in[8];
    const float* ln1_b = (const float*)d_in[9];
    const float* ln2_w = (const float*)d_in[10];
    const float* ln2_b = (const float*)d_in[11];
    const float* ff1_w = (const float*)d_in[12];
    const float* ff1_b = (const float*)d_in[13];
    const float* ff2_w = (const float*)d_in[14];
    const float* ff2_b = (const float*)d_in[15];
    const float* ca_qkv_w = (const float*)d_in[16];
    const float* ca_qkv_b = (const float*)d_in[17];
    const float* ca_out_w = (const float*)d_in[18];
    const float* ca_out_b = (const float*)d_in[19];
    const float* ca_ln_w  = (const float*)d_in[20];
    const float* ca_ln_b  = (const float*)d_in[21];
    const float* norm_w   = (const float*)d_in[22];
    const float* norm_b   = (const float*)d_in[23];
    float* out = (float*)d_out;

    char* ws = (char*)d_ws;
    const size_t MB = 1024*1024;
    float*          x     = (float*)(ws);                    // [0,16M)
    char*           bufA  = ws + 16*MB;                      // [16,48M) qkvb/ff1b/kvf
    float*          bufB  = (float*)(ws + 48*MB);            // [48,64M) proj/ff2 f32
    unsigned short* vtb   = (unsigned short*)(ws + 48*MB);   // aliases bufB (disjoint lifetime)
    unsigned short* ob    = (unsigned short*)(ws + 64*MB);   // [64,72M)
    unsigned short* xb    = (unsigned short*)(ws + 72*MB);   // [72,80M)
    unsigned short* qkvw_b = (unsigned short*)(ws + 80*MB);
    unsigned short* outw_b = (unsigned short*)(ws + 83*MB);
    unsigned short* ff1w_b = (unsigned short*)(ws + 84*MB);
    unsigned short* ff2w_b = (unsigned short*)(ws + 88*MB);
    unsigned short* kvw_b  = (unsigned short*)(ws + 92*MB);

    unsigned short* qkvb = (unsigned short*)bufA;   // bf16 [8192][1024] ([q|k])
    unsigned short* ff1b = (unsigned short*)bufA;   // bf16 [8192][2048]
    float*          kvf  = (float*)bufA;            // f32  [8192][1024]

    const int M = B_ * S_;

    // 0. one-time weight casts to bf16 (single launch)
    cast5_kernel<<<(C0_+C1_+C2_+C3_+C4_+255)/256, 256, 0, stream>>>(
        qkv_w, out_w, ff1_w, ff2_w, ca_qkv_w + 512*512,
        qkvw_b, outw_b, ff1w_b, ff2w_b, kvw_b);

    // 1. byte embedding + n-gram hash adds
    embed_ngram_kernel<<<M, 128, 0, stream>>>(byte_seq, byte_emb, ng_emb, x, xb);

    // 2. transformer layers
    for (int l = 0; l < L_; ++l) {
        mgemm_kernel<0,1,128,1,0><<<dim3(1536/128, M/128), 256, 0, stream>>>(
            xb, qkvw_b + (size_t)l*1536*D_, qkv_b + l*1536, qkvb, vtb, nullptr, M, 1536, D_);
        attn_mfma_kernel<<<dim3(S_/128, B_*H_), 256, 0, stream>>>(qkvb, vtb, ob);
        mgemm_kernel<0,0,64,0,1><<<dim3(D_/64, M/128), 256, 0, stream>>>(
            ob, outw_b + (size_t)l*D_*D_, out_b + l*D_, bufB, nullptr, x, M, D_, D_);
        ln_kernel<<<M, 256, 0, stream>>>(x, xb, bufB, nullptr, ln1_w + l*D_, ln1_b + l*D_, 1e-5f);
        mgemm_kernel<1,1,128,0,0><<<dim3(2048/128, M/128), 256, 0, stream>>>(
            xb, ff1w_b + (size_t)l*2048*D_, ff1_b + l*2048, ff1b, nullptr, nullptr, M, 2048, D_);
        mgemm_kernel<0,0,64,0,1><<<dim3(D_/64, M/128), 256, 0, stream>>>(
            ff1b, ff2w_b + (size_t)l*D_*2048, ff2_b + l*D_, bufB, nullptr, x, M, D_, 2048);
        ln_kernel<<<M, 256, 0, stream>>>(x, xb, bufB, nullptr, ln2_w + l*D_, ln2_b + l*D_, 1e-5f);
    }

    // 3. dual LN (final out + kvn bf16, one pass) -> kv mgemm -> fused tail
    ln_dual_kernel<<<M, 256, 0, stream>>>(out, xb, x, norm_w, norm_b, ca_ln_w, ca_ln_b);
    mgemm_kernel<0,0,128,0,0><<<dim3(1024/128, M/128), 256, 0, stream>>>(
        xb, kvw_b, ca_qkv_b + 512, kvf, nullptr, nullptr, M, 1024, D_);
    patch_tail_kernel<<<B_*NPATCH_, 256, 0, stream>>>(
        x, kvf, ca_qkv_w, ca_qkv_b, ca_out_w, ca_out_b,
        ca_ln_w, ca_ln_b, norm_w, norm_b, out);
}

// Round 16
// 505.388 us; speedup vs baseline: 1.0827x; 1.0010x over previous
//
#include <hip/hip_runtime.h>
#include <hip/hip_bf16.h>

#define B_ 4
#define S_ 2048
#define D_ 512
#define H_ 8
#define HD_ 64
#define L_ 2
#define V_ 30000
#define NPATCH_ 16
#define PLEN_ 128

typedef short bf16x8 __attribute__((ext_vector_type(8)));
typedef float f32x4 __attribute__((ext_vector_type(4)));

__device__ __forceinline__ unsigned short f2bf(float f) {
    unsigned u = __float_as_uint(f);
    return (unsigned short)((u + 0x7FFFu + ((u >> 16) & 1u)) >> 16);   // RNE
}
__device__ __forceinline__ float bf2f(unsigned short u) {
    return __uint_as_float(((unsigned int)u) << 16);
}

// ---------------- merged f32 -> bf16 weight casts (1 launch) ----------------
#define C0_ (2*1536*512/4)
#define C1_ (2*512*512/4)
#define C2_ (2*2048*512/4)
#define C3_ (2*512*2048/4)
#define C4_ (1024*512/4)
__global__ __launch_bounds__(256) void cast5_kernel(
    const float* __restrict__ s0, const float* __restrict__ s1,
    const float* __restrict__ s2, const float* __restrict__ s3,
    const float* __restrict__ s4,
    unsigned short* __restrict__ d0, unsigned short* __restrict__ d1,
    unsigned short* __restrict__ d2, unsigned short* __restrict__ d3,
    unsigned short* __restrict__ d4)
{
    int i = blockIdx.x * 256 + threadIdx.x;
    const float* s; unsigned short* d;
    if      (i < C0_)                  { s = s0; d = d0; }
    else if ((i -= C0_) < C1_)         { s = s1; d = d1; }
    else if ((i -= C1_) < C2_)         { s = s2; d = d2; }
    else if ((i -= C2_) < C3_)         { s = s3; d = d3; }
    else if ((i -= C3_) < C4_)         { s = s4; d = d4; }
    else return;
    const float4 v = *reinterpret_cast<const float4*>(s + (size_t)i * 4);
    ushort4 o;
    o.x = f2bf(v.x); o.y = f2bf(v.y); o.z = f2bf(v.z); o.w = f2bf(v.w);
    *reinterpret_cast<ushort4*>(d + (size_t)i * 4) = o;
}

// ---------------- embed + n-gram hash add (f32 + bf16 shadow) -------------
__global__ __launch_bounds__(128) void embed_ngram_kernel(
    const int* __restrict__ bytes, const float* __restrict__ byte_emb,
    const float* __restrict__ ng_emb, float* __restrict__ x,
    unsigned short* __restrict__ xb)
{
    const int bs = blockIdx.x;
    const int s  = bs % S_;
    const int b  = bs / S_;
    const int d  = threadIdx.x * 4;
    const int* brow = bytes + (size_t)b * S_;

    const int c = brow[s];
    float4 v = *reinterpret_cast<const float4*>(byte_emb + (size_t)c * D_ + d);

    if (s >= 2) {
        int h = (brow[s-2]*961 + brow[s-1]*31 + brow[s]) % V_;
        const float4 g = *reinterpret_cast<const float4*>(ng_emb + ((size_t)0*V_ + h)*D_ + d);
        v.x += 0.25f*g.x; v.y += 0.25f*g.y; v.z += 0.25f*g.z; v.w += 0.25f*g.w;
    }
    if (s >= 3) {
        int h = (brow[s-3]*29791 + brow[s-2]*961 + brow[s-1]*31 + brow[s]) % V_;
        const float4 g = *reinterpret_cast<const float4*>(ng_emb + ((size_t)1*V_ + h)*D_ + d);
        v.x += 0.25f*g.x; v.y += 0.25f*g.y; v.z += 0.25f*g.z; v.w += 0.25f*g.w;
    }
    if (s >= 4) {
        int h = (brow[s-4]*23521 + brow[s-3]*29791 + brow[s-2]*961 + brow[s-1]*31 + brow[s]) % V_;
        const float4 g = *reinterpret_cast<const float4*>(ng_emb + ((size_t)2*V_ + h)*D_ + d);
        v.x += 0.25f*g.x; v.y += 0.25f*g.y; v.z += 0.25f*g.z; v.w += 0.25f*g.w;
    }
    *reinterpret_cast<float4*>(x + (size_t)bs * D_ + d) = v;
    ushort4 o;
    o.x = f2bf(v.x); o.y = f2bf(v.y); o.z = f2bf(v.z); o.w = f2bf(v.w);
    *reinterpret_cast<ushort4*>(xb + (size_t)bs * D_ + d) = o;
}

// ---------------- MFMA bf16 GEMM: Y = X @ W^T + bias [,relu][,+resid] ------
// DBUF=1 (BN=64 / proj+ff2 only): double-buffered LDS, stage tile t+1 issued
// BEFORE computing tile t -> barrier's vmcnt drain overlaps compute
// (T3-minimum). LDS 48KB still allows 3 blocks/CU; those grids are
// grid-limited to 2/CU so no occupancy loss. BN=128 stays single-buffered
// (64KB would cut 3-4 blocks/CU to 2 - m132 regression mode).
template<int DO_RELU, int BF16OUT, int BN, int VT, int RESID, int DBUF>
__global__ __launch_bounds__(256) void mgemm_kernel(
    const unsigned short* __restrict__ Xb, const unsigned short* __restrict__ Wb,
    const float* __restrict__ bias, void* __restrict__ Yout,
    unsigned short* __restrict__ vtb, const float* __restrict__ resid,
    int M, int N, int K)
{
    constexpr int NT  = BN / 32;
    constexpr int NLB = BN / 32;
    constexpr int NB  = DBUF ? 2 : 1;
    __shared__ unsigned short As[NB*128*64];
    __shared__ unsigned short Bs[NB*BN*64];

    const int t    = threadIdx.x;
    const int lane = t & 63;
    const int w    = t >> 6;

    const int nwg = gridDim.x * gridDim.y;
    const int bid = blockIdx.y * gridDim.x + blockIdx.x;
    const int swz = (bid & 7) * (nwg >> 3) + (bid >> 3);
    const int bx  = swz % gridDim.x, by = swz / gridDim.x;

    const int bm   = by * 128, bn = bx * BN;
    const int l15  = lane & 15, lg = lane >> 4;
    const int wr   = w >> 1, wc = w & 1;

    int srow[4], scol[4];
#pragma unroll
    for (int i = 0; i < 4; ++i) {
        const int off = w*1024 + i*4096 + lane*16;
        srow[i] = off >> 7;
        scol[i] = ((off >> 4) & 7) ^ (srow[i] & 7);
    }

    f32x4 acc[4][NT];
#pragma unroll
    for (int mt = 0; mt < 4; ++mt)
#pragma unroll
        for (int nt = 0; nt < NT; ++nt) acc[mt][nt] = (f32x4){0.f,0.f,0.f,0.f};

    auto STAGE = [&](int bufi, int kt) {
#pragma unroll
        for (int i = 0; i < 4; ++i) {
            const unsigned short* gA = Xb + (size_t)(bm + srow[i]) * K + kt + scol[i]*8;
            __builtin_amdgcn_global_load_lds(
                (const __attribute__((address_space(1))) void*)gA,
                (__attribute__((address_space(3))) void*)&As[bufi*128*64 + w*512 + i*2048], 16, 0, 0);
        }
#pragma unroll
        for (int i = 0; i < NLB; ++i) {
            const unsigned short* gB = Wb + (size_t)(bn + srow[i]) * K + kt + scol[i]*8;
            __builtin_amdgcn_global_load_lds(
                (const __attribute__((address_space(1))) void*)gB,
                (__attribute__((address_space(3))) void*)&Bs[bufi*BN*64 + w*512 + i*2048], 16, 0, 0);
        }
    };

    auto COMPUTE = [&](const unsigned short* Ab, const unsigned short* Bb) {
#pragma unroll
        for (int ks = 0; ks < 2; ++ks) {
            const int c16 = (ks*4 + lg) ^ (l15 & 7);
            bf16x8 a[4], b[NT];
#pragma unroll
            for (int mt = 0; mt < 4; ++mt)
                a[mt] = *reinterpret_cast<const bf16x8*>(&Ab[(wr*64 + mt*16 + l15)*64 + c16*8]);
#pragma unroll
            for (int nt = 0; nt < NT; ++nt)
                b[nt] = *reinterpret_cast<const bf16x8*>(&Bb[(wc*(BN/2) + nt*16 + l15)*64 + c16*8]);
#pragma unroll
            for (int mt = 0; mt < 4; ++mt)
#pragma unroll
                for (int nt = 0; nt < NT; ++nt)
                    acc[mt][nt] = __builtin_amdgcn_mfma_f32_16x16x32_bf16(
                        a[mt], b[nt], acc[mt][nt], 0, 0, 0);
        }
    };

    if constexpr (DBUF) {
        STAGE(0, 0);
        __syncthreads();                       // drain prologue stage
        const int niter = K >> 6;
        for (int it = 0; it < niter; ++it) {
            const int cur = it & 1;
            if (it + 1 < niter) STAGE(cur ^ 1, (it + 1) << 6);
            COMPUTE(&As[cur*128*64], &Bs[cur*BN*64]);
            __syncthreads();                   // vmcnt drain overlapped by COMPUTE
        }
    } else {
        for (int kt = 0; kt < K; kt += 64) {
            STAGE(0, kt);
            __syncthreads();
            COMPUTE(As, Bs);
            __syncthreads();
        }
    }

    float bv[NT];
#pragma unroll
    for (int nt = 0; nt < NT; ++nt) bv[nt] = bias[bn + wc*(BN/2) + nt*16 + l15];

#pragma unroll
    for (int mt = 0; mt < 4; ++mt) {
#pragma unroll
        for (int nt = 0; nt < NT; ++nt) {
            const int n = bn + wc*(BN/2) + nt*16 + l15;
#pragma unroll
            for (int r = 0; r < 4; ++r) {
                const int m = bm + wr*64 + mt*16 + 4*lg + r;
                float v = acc[mt][nt][r] + bv[nt];
                if (DO_RELU) v = fmaxf(v, 0.f);
                if (RESID) v += resid[(size_t)m * N + n];
                if constexpr (VT) {
                    if (n < 1024)
                        ((unsigned short*)Yout)[(size_t)m * 1024 + n] = f2bf(v);
                    else
                        vtb[((size_t)(m >> 11) * 512 + (n - 1024)) * 2048 + (m & 2047)] = f2bf(v);
                } else if constexpr (BF16OUT) {
                    ((unsigned short*)Yout)[(size_t)m * N + n] = f2bf(v);
                } else {
                    ((float*)Yout)[(size_t)m * N + n] = v;
                }
            }
        }
    }
}

// ---------------- MFMA bf16 causal flash attention (round-13 proven) -------
__global__ __launch_bounds__(256) void attn_mfma_kernel(
    const unsigned short* __restrict__ qkvb, const unsigned short* __restrict__ vtb,
    unsigned short* __restrict__ ob)
{
    __shared__ unsigned short Ks[128*72];
    __shared__ unsigned short Vt[64*136];
    __shared__ unsigned short Plds[4*16*136];

    const int t    = threadIdx.x;
    const int lane = t & 63;
    const int w    = t >> 6;
    const int qp   = blockIdx.x;
    const int bh   = blockIdx.y;
    const int h    = bh & 7;
    const int b    = bh >> 3;

    const unsigned short* base = qkvb + (size_t)b * S_ * 1024;
    const int l15 = lane & 15, lg = lane >> 4;
    const int skey = t >> 1;
    const int sd0  = (t & 1) * 32;
    const int sdv  = t >> 2;
    const int skc  = (t & 3) * 32;
    const unsigned short* vbase = vtb + ((size_t)b * 512 + h*64 + sdv) * 2048;
    unsigned short* pw_base = Plds + w*16*136;
    const int pxor = ((l15 >> 3) & 1) << 1;

    bf16x8 kr0, kr1, kr2, kr3, vr0, vr1, vr2, vr3;
#define LOADREG(KT) { \
        const unsigned short* pk_ = base + (size_t)((KT) + skey) * 1024 + 512 + h*64 + sd0; \
        kr0 = *reinterpret_cast<const bf16x8*>(pk_);       \
        kr1 = *reinterpret_cast<const bf16x8*>(pk_ + 8);   \
        kr2 = *reinterpret_cast<const bf16x8*>(pk_ + 16);  \
        kr3 = *reinterpret_cast<const bf16x8*>(pk_ + 24);  \
        const unsigned short* pv_ = vbase + (KT) + skc;    \
        vr0 = *reinterpret_cast<const bf16x8*>(pv_);       \
        vr1 = *reinterpret_cast<const bf16x8*>(pv_ + 8);   \
        vr2 = *reinterpret_cast<const bf16x8*>(pv_ + 16);  \
        vr3 = *reinterpret_cast<const bf16x8*>(pv_ + 24); }

    LOADREG(0);

#pragma unroll
    for (int half = 0; half < 2; ++half) {
        const int qb  = half ? (31 - qp) : qp;
        const int q0w = qb * 64 + w * 16;

        bf16x8 qf0, qf1;
        {
            const unsigned short* qr = base + (size_t)(q0w + l15) * 1024 + h*64 + lg*8;
            qf0 = *reinterpret_cast<const bf16x8*>(qr);
            qf1 = *reinterpret_cast<const bf16x8*>(qr + 32);
        }

        f32x4 oacc[4];
#pragma unroll
        for (int i = 0; i < 4; ++i) oacc[i] = (f32x4){0.f,0.f,0.f,0.f};
        float mrow[4] = {-INFINITY,-INFINITY,-INFINITY,-INFINITY};
        float lrow[4] = {0.f,0.f,0.f,0.f};

        const int ntiles = (qb + 2) >> 1;
        for (int tile = 0; tile < ntiles; ++tile) {
            const int kt = tile * 128;
            __syncthreads();
            *reinterpret_cast<bf16x8*>(&Ks[skey*72 + sd0])      = kr0;
            *reinterpret_cast<bf16x8*>(&Ks[skey*72 + sd0 + 8])  = kr1;
            *reinterpret_cast<bf16x8*>(&Ks[skey*72 + sd0 + 16]) = kr2;
            *reinterpret_cast<bf16x8*>(&Ks[skey*72 + sd0 + 24]) = kr3;
            *reinterpret_cast<bf16x8*>(&Vt[sdv*136 + skc])      = vr0;
            *reinterpret_cast<bf16x8*>(&Vt[sdv*136 + skc + 8])  = vr1;
            *reinterpret_cast<bf16x8*>(&Vt[sdv*136 + skc + 16]) = vr2;
            *reinterpret_cast<bf16x8*>(&Vt[sdv*136 + skc + 24]) = vr3;
            __syncthreads();
            const int nkt = (tile + 1 < ntiles) ? (kt + 128) : 0;
            LOADREG(nkt);

            f32x4 sacc[8];
            __builtin_amdgcn_s_setprio(1);
#pragma unroll
            for (int kt16 = 0; kt16 < 8; ++kt16) {
                sacc[kt16] = (f32x4){0.f,0.f,0.f,0.f};
                const unsigned short* kp = &Ks[(kt16*16 + l15)*72 + lg*8];
                bf16x8 k0 = *reinterpret_cast<const bf16x8*>(kp);
                bf16x8 k1 = *reinterpret_cast<const bf16x8*>(kp + 32);
                sacc[kt16] = __builtin_amdgcn_mfma_f32_16x16x32_bf16(qf0, k0, sacc[kt16], 0, 0, 0);
                sacc[kt16] = __builtin_amdgcn_mfma_f32_16x16x32_bf16(qf1, k1, sacc[kt16], 0, 0, 0);
            }
            __builtin_amdgcn_s_setprio(0);

            const bool diag = (tile == ntiles - 1);
#pragma unroll
            for (int kt16 = 0; kt16 < 8; ++kt16) {
#pragma unroll
                for (int r = 0; r < 4; ++r) {
                    float s = sacc[kt16][r] * 0.125f;
                    if (diag) {
                        const int key = kt + kt16*16 + l15;
                        const int q   = q0w + 4*lg + r;
                        if (key > q) s = -INFINITY;
                    }
                    sacc[kt16][r] = s;
                }
            }
#pragma unroll
            for (int r = 0; r < 4; ++r) {
                float tm = fmaxf(
                    fmaxf(fmaxf(sacc[0][r], sacc[1][r]), fmaxf(sacc[2][r], sacc[3][r])),
                    fmaxf(fmaxf(sacc[4][r], sacc[5][r]), fmaxf(sacc[6][r], sacc[7][r])));
#pragma unroll
                for (int off = 8; off; off >>= 1) tm = fmaxf(tm, __shfl_xor(tm, off, 64));
                const float nm = fmaxf(mrow[r], tm);
                const float al = __expf(mrow[r] - nm);
                mrow[r] = nm;
                float ps = 0.f;
                const int prow = (4*lg + r)*136;
                const int cswz = ((lg & 2) << 3);
#pragma unroll
                for (int kt16 = 0; kt16 < 8; ++kt16) {
                    const float p = __expf(sacc[kt16][r] - nm);
                    ps += p;
                    pw_base[prow + ((kt16*16 + l15) ^ cswz)] = f2bf(p);
                }
#pragma unroll
                for (int off = 8; off; off >>= 1) ps += __shfl_xor(ps, off, 64);
                lrow[r] = lrow[r]*al + ps;
#pragma unroll
                for (int dt = 0; dt < 4; ++dt) oacc[dt][r] *= al;
            }

            const unsigned short* pr = &pw_base[l15*136];
            bf16x8 pa0 = *reinterpret_cast<const bf16x8*>(&pr[(( 0 + lg) ^ pxor)*8]);
            bf16x8 pa1 = *reinterpret_cast<const bf16x8*>(&pr[(( 4 + lg) ^ pxor)*8]);
            bf16x8 pa2 = *reinterpret_cast<const bf16x8*>(&pr[(( 8 + lg) ^ pxor)*8]);
            bf16x8 pa3 = *reinterpret_cast<const bf16x8*>(&pr[((12 + lg) ^ pxor)*8]);
            __builtin_amdgcn_s_setprio(1);
#pragma unroll
            for (int dt = 0; dt < 4; ++dt) {
                const unsigned short* vrow = &Vt[(dt*16 + l15)*136];
                bf16x8 v0 = *reinterpret_cast<const bf16x8*>(&vrow[( 0 + lg)*8]);
                bf16x8 v1 = *reinterpret_cast<const bf16x8*>(&vrow[( 4 + lg)*8]);
                bf16x8 v2 = *reinterpret_cast<const bf16x8*>(&vrow[( 8 + lg)*8]);
                bf16x8 v3 = *reinterpret_cast<const bf16x8*>(&vrow[(12 + lg)*8]);
                oacc[dt] = __builtin_amdgcn_mfma_f32_16x16x32_bf16(pa0, v0, oacc[dt], 0, 0, 0);
                oacc[dt] = __builtin_amdgcn_mfma_f32_16x16x32_bf16(pa1, v1, oacc[dt], 0, 0, 0);
                oacc[dt] = __builtin_amdgcn_mfma_f32_16x16x32_bf16(pa2, v2, oacc[dt], 0, 0, 0);
                oacc[dt] = __builtin_amdgcn_mfma_f32_16x16x32_bf16(pa3, v3, oacc[dt], 0, 0, 0);
            }
            __builtin_amdgcn_s_setprio(0);
        }

#pragma unroll
        for (int dt = 0; dt < 4; ++dt) {
#pragma unroll
            for (int r = 0; r < 4; ++r) {
                const int q = q0w + 4*lg + r;
                ob[((size_t)b*S_ + q)*D_ + h*64 + dt*16 + l15] = f2bf(oacc[dt][r] / lrow[r]);
            }
        }
    }
#undef LOADREG
}

// ---------------- LayerNorm (residual add, nullable outputs) ---------------
__global__ __launch_bounds__(256) void ln_kernel(
    float* __restrict__ dst, unsigned short* __restrict__ dst2,
    const float* __restrict__ src, const float* __restrict__ add,
    const float* __restrict__ w, const float* __restrict__ b, float eps)
{
    const int row = blockIdx.x, tid = threadIdx.x;
    const int lane = tid & 63, wave = tid >> 6;
    float2 v = *reinterpret_cast<const float2*>(src + (size_t)row * D_ + tid*2);
    if (add) {
        float2 a = *reinterpret_cast<const float2*>(add + (size_t)row * D_ + tid*2);
        v.x += a.x; v.y += a.y;
    }
    __shared__ float red[8];
    float s = v.x + v.y;
#pragma unroll
    for (int off = 32; off; off >>= 1) s += __shfl_xor(s, off, 64);
    if (lane == 0) red[wave] = s;
    __syncthreads();
    const float mean = (red[0]+red[1]+red[2]+red[3]) * (1.f/D_);
    const float d0 = v.x - mean, d1 = v.y - mean;
    float sq = d0*d0 + d1*d1;
#pragma unroll
    for (int off = 32; off; off >>= 1) sq += __shfl_xor(sq, off, 64);
    if (lane == 0) red[4+wave] = sq;
    __syncthreads();
    const float var = (red[4]+red[5]+red[6]+red[7]) * (1.f/D_);
    const float inv = rsqrtf(var + eps);
    const float o0 = d0*inv*w[tid*2] + b[tid*2];
    const float o1 = d1*inv*w[tid*2+1] + b[tid*2+1];
    if (dst)
        *reinterpret_cast<float2*>(dst + (size_t)row * D_ + tid*2) = make_float2(o0, o1);
    if (dst2) {
        ushort2 u; u.x = f2bf(o0); u.y = f2bf(o1);
        *reinterpret_cast<ushort2*>(dst2 + (size_t)row * D_ + tid*2) = u;
    }
}

// ---------------- dual LayerNorm: one read of x -> final out (f32) + kvn (bf16)
__global__ __launch_bounds__(256) void ln_dual_kernel(
    float* __restrict__ out, unsigned short* __restrict__ kvnb,
    const float* __restrict__ src,
    const float* __restrict__ nw, const float* __restrict__ nb,
    const float* __restrict__ cw, const float* __restrict__ cb)
{
    const int row = blockIdx.x, tid = threadIdx.x;
    const int lane = tid & 63, wave = tid >> 6;
    float2 v = *reinterpret_cast<const float2*>(src + (size_t)row * D_ + tid*2);
    __shared__ float red[8];
    float s = v.x + v.y;
#pragma unroll
    for (int off = 32; off; off >>= 1) s += __shfl_xor(s, off, 64);
    if (lane == 0) red[wave] = s;
    __syncthreads();
    const float mean = (red[0]+red[1]+red[2]+red[3]) * (1.f/D_);
    const float d0 = v.x - mean, d1 = v.y - mean;
    float sq = d0*d0 + d1*d1;
#pragma unroll
    for (int off = 32; off; off >>= 1) sq += __shfl_xor(sq, off, 64);
    if (lane == 0) red[4+wave] = sq;
    __syncthreads();
    const float var = (red[4]+red[5]+red[6]+red[7]) * (1.f/D_);
    const float inv = rsqrtf(var + 1e-6f);
    const float n0 = d0*inv;
    const float n1 = d1*inv;
    *reinterpret_cast<float2*>(out + (size_t)row * D_ + tid*2) =
        make_float2(n0*nw[tid*2] + nb[tid*2], n1*nw[tid*2+1] + nb[tid*2+1]);
    ushort2 u;
    u.x = f2bf(n0*cw[tid*2]   + cb[tid*2]);
    u.y = f2bf(n1*cw[tid*2+1] + cb[tid*2+1]);
    *reinterpret_cast<ushort2*>(kvnb + (size_t)row * D_ + tid*2) = u;
}

// ---------------- fused patch-CA tail ----------------
__global__ __launch_bounds__(256) void patch_tail_kernel(
    const float* __restrict__ x, const float* __restrict__ kvf,
    const float* __restrict__ ca_qkv_w, const float* __restrict__ ca_qkv_b,
    const float* __restrict__ ca_out_w, const float* __restrict__ ca_out_b,
    const float* __restrict__ ca_ln_w, const float* __restrict__ ca_ln_b,
    const float* __restrict__ norm_w, const float* __restrict__ norm_b,
    float* __restrict__ out)
{
    __shared__ float query[512];
    __shared__ float qs[512];
    __shared__ float ps[8*128];
    __shared__ float os[512];
    __shared__ float red[64];
    __shared__ float mred[8], sred[8];

    const int t  = threadIdx.x;
    const int bp = blockIdx.x;
    const int d0 = t * 2;
    const int lane = t & 63, wave = t >> 6;

    {
        const float* base = x + (size_t)bp * PLEN_ * D_ + d0;
        float s0 = 0.f, s1 = 0.f;
        for (int l = 0; l < PLEN_; ++l) {
            float2 v = *reinterpret_cast<const float2*>(base + (size_t)l * D_);
            s0 += v.x; s1 += v.y;
        }
        query[d0] = s0 * (1.f/PLEN_);
        query[d0+1] = s1 * (1.f/PLEN_);
    }
    __syncthreads();

    float qv0 = query[d0], qv1 = query[d0+1];
    {
        float s = qv0 + qv1;
#pragma unroll
        for (int off = 32; off; off >>= 1) s += __shfl_xor(s, off, 64);
        if (lane == 0) red[wave] = s;
        __syncthreads();
        const float mean = (red[0]+red[1]+red[2]+red[3]) * (1.f/D_);
        const float e0 = qv0 - mean, e1 = qv1 - mean;
        float sq = e0*e0 + e1*e1;
#pragma unroll
        for (int off = 32; off; off >>= 1) sq += __shfl_xor(sq, off, 64);
        if (lane == 0) red[4+wave] = sq;
        __syncthreads();
        const float var = (red[4]+red[5]+red[6]+red[7]) * (1.f/D_);
        const float inv = rsqrtf(var + 1e-6f);
        qs[d0]   = e0*inv*ca_ln_w[d0]   + ca_ln_b[d0];
        qs[d0+1] = e1*inv*ca_ln_w[d0+1] + ca_ln_b[d0+1];
    }
    __syncthreads();

    float qp0, qp1;
    {
        const float* w0 = ca_qkv_w + (size_t)d0 * D_;
        float a0 = ca_qkv_b[d0], a1 = ca_qkv_b[d0+1];
        for (int e = 0; e < D_; e += 4) {
            const float4 qn4 = *reinterpret_cast<const float4*>(&qs[e]);
            const float4 wa = *reinterpret_cast<const float4*>(w0 + e);
            const float4 wb = *reinterpret_cast<const float4*>(w0 + D_ + e);
            a0 += qn4.x*wa.x + qn4.y*wa.y + qn4.z*wa.z + qn4.w*wa.w;
            a1 += qn4.x*wb.x + qn4.y*wb.y + qn4.z*wb.z + qn4.w*wb.w;
        }
        qp0 = a0 * 0.125f; qp1 = a1 * 0.125f;
    }
    __syncthreads();
    qs[d0] = qp0; qs[d0+1] = qp1;
    __syncthreads();

    {
        const int h = t >> 5, c = t & 31;
        const float* qh = &qs[h*64];
#pragma unroll
        for (int j = 0; j < 4; ++j) {
            const int l = c*4 + j;
            const float* krow = kvf + ((size_t)bp*PLEN_ + l)*1024 + h*64;
            float acc = 0.f;
            for (int e = 0; e < 64; e += 4) {
                const float4 qe = *reinterpret_cast<const float4*>(qh + e);
                const float4 ke = *reinterpret_cast<const float4*>(krow + e);
                acc += qe.x*ke.x + qe.y*ke.y + qe.z*ke.z + qe.w*ke.w;
            }
            ps[h*128 + l] = acc;
        }
    }
    __syncthreads();

    {
        const int h = t >> 5, c = t & 31;
        float m4 = fmaxf(fmaxf(ps[h*128+c*4], ps[h*128+c*4+1]),
                         fmaxf(ps[h*128+c*4+2], ps[h*128+c*4+3]));
        red[h*8 + (c>>2)] = 0.f;
        __syncthreads();
        float mt_ = m4;
#pragma unroll
        for (int off = 1; off < 4; off <<= 1) mt_ = fmaxf(mt_, __shfl_xor(mt_, off, 64));
        if ((c & 3) == 0) red[h*8 + (c>>2)] = mt_;
        __syncthreads();
        if (t < 8) {
            float m = red[t*8];
#pragma unroll
            for (int j = 1; j < 8; ++j) m = fmaxf(m, red[t*8+j]);
            mred[t] = m;
        }
        __syncthreads();
        const float mh = mred[h];
        float ssum = 0.f;
#pragma unroll
        for (int j = 0; j < 4; ++j) {
            const float p = __expf(ps[h*128 + c*4 + j] - mh);
            ps[h*128 + c*4 + j] = p;
            ssum += p;
        }
#pragma unroll
        for (int off = 1; off < 4; off <<= 1) ssum += __shfl_xor(ssum, off, 64);
        if ((c & 3) == 0) red[h*8 + (c>>2)] = ssum;
        __syncthreads();
        if (t < 8) {
            float s = 0.f;
#pragma unroll
            for (int j = 0; j < 8; ++j) s += red[t*8+j];
            sred[t] = 1.f / s;
        }
    }
    __syncthreads();

    {
        const int h = t >> 5;
        const float* vbase = kvf + (size_t)bp*PLEN_*1024 + 512 + d0;
        float a0 = 0.f, a1 = 0.f;
        const float* ph = &ps[h*128];
        for (int l = 0; l < PLEN_; ++l) {
            const float p = ph[l];
            const float2 vv = *reinterpret_cast<const float2*>(vbase + (size_t)l*1024);
            a0 += p * vv.x; a1 += p * vv.y;
        }
        os[d0]   = a0 * sred[h];
        os[d0+1] = a1 * sred[h];
    }
    __syncthreads();

    float r0, r1;
    {
        const float* w0 = ca_out_w + (size_t)d0 * D_;
        float a0 = ca_out_b[d0], a1 = ca_out_b[d0+1];
        for (int e = 0; e < D_; e += 4) {
            const float4 oe = *reinterpret_cast<const float4*>(&os[e]);
            const float4 wa = *reinterpret_cast<const float4*>(w0 + e);
            const float4 wb = *reinterpret_cast<const float4*>(w0 + D_ + e);
            a0 += oe.x*wa.x + oe.y*wa.y + oe.z*wa.z + oe.w*wa.w;
            a1 += oe.x*wb.x + oe.y*wb.y + oe.z*wb.z + oe.w*wb.w;
        }
        r0 = query[d0] + a0;
        r1 = query[d0+1] + a1;
    }
    {
        float s = r0 + r1;
#pragma unroll
        for (int off = 32; off; off >>= 1) s += __shfl_xor(s, off, 64);
        __syncthreads();
        if (lane == 0) red[wave] = s;
        __syncthreads();
        const float mean = (red[0]+red[1]+red[2]+red[3]) * (1.f/D_);
        const float e0 = r0 - mean, e1 = r1 - mean;
        float sq = e0*e0 + e1*e1;
#pragma unroll
        for (int off = 32; off; off >>= 1) sq += __shfl_xor(sq, off, 64);
        if (lane == 0) red[4+wave] = sq;
        __syncthreads();
        const float var = (red[4]+red[5]+red[6]+red[7]) * (1.f/D_);
        const float inv = rsqrtf(var + 1e-6f);
        float* orow = out + ((size_t)(B_*S_) + bp) * D_;
        orow[d0]   = e0*inv*norm_w[d0]   + norm_b[d0];
        orow[d0+1] = e1*inv*norm_w[d0+1] + norm_b[d0+1];
    }
}

extern "C" void kernel_launch(void* const* d_in, const int* in_sizes, int n_in,
                              void* d_out, int out_size, void* d_ws, size_t ws_size,
                              hipStream_t stream)
{
    const int*   byte_seq = (const int*)d_in[0];
    const float* byte_emb = (const float*)d_in[2];
    const float* ng_emb   = (const float*)d_in[3];
    const float* qkv_w = (const float*)d_in[4];
    const float* qkv_b = (const float*)d_in[5];
    const float* out_w = (const float*)d_in[6];
    const float* out_b = (const float*)d_in[7];
    const float* ln1_w = (const float*)d_in[8];
    const float* ln1_b = (const float*)d_in[9];
    const float* ln2_w = (const float*)d_in[10];
    const float* ln2_b = (const float*)d_in[11];
    const float* ff1_w = (const float*)d_in[12];
    const float* ff1_b = (const float*)d_in[13];
    const float* ff2_w = (const float*)d_in[14];
    const float* ff2_b = (const float*)d_in[15];
    const float* ca_qkv_w = (const float*)d_in[16];
    const float* ca_qkv_b = (const float*)d_in[17];
    const float* ca_out_w = (const float*)d_in[18];
    const float* ca_out_b = (const float*)d_in[19];
    const float* ca_ln_w  = (const float*)d_in[20];
    const float* ca_ln_b  = (const float*)d_in[21];
    const float* norm_w   = (const float*)d_in[22];
    const float* norm_b   = (const float*)d_in[23];
    float* out = (float*)d_out;

    char* ws = (char*)d_ws;
    const size_t MB = 1024*1024;
    float*          x     = (float*)(ws);                    // [0,16M)
    char*           bufA  = ws + 16*MB;                      // [16,48M) qkvb/ff1b/kvf
    float*          bufB  = (float*)(ws + 48*MB);            // [48,64M) proj/ff2 f32
    unsigned short* vtb   = (unsigned short*)(ws + 48*MB);   // aliases bufB (disjoint lifetime)
    unsigned short* ob    = (unsigned short*)(ws + 64*MB);   // [64,72M)
    unsigned short* xb    = (unsigned short*)(ws + 72*MB);   // [72,80M)
    unsigned short* qkvw_b = (unsigned short*)(ws + 80*MB);
    unsigned short* outw_b = (unsigned short*)(ws + 83*MB);
    unsigned short* ff1w_b = (unsigned short*)(ws + 84*MB);
    unsigned short* ff2w_b = (unsigned short*)(ws + 88*MB);
    unsigned short* kvw_b  = (unsigned short*)(ws + 92*MB);

    unsigned short* qkvb = (unsigned short*)bufA;   // bf16 [8192][1024] ([q|k])
    unsigned short* ff1b = (unsigned short*)bufA;   // bf16 [8192][2048]
    float*          kvf  = (float*)bufA;            // f32  [8192][1024]

    const int M = B_ * S_;

    // 0. one-time weight casts to bf16 (single launch)
    cast5_kernel<<<(C0_+C1_+C2_+C3_+C4_+255)/256, 256, 0, stream>>>(
        qkv_w, out_w, ff1_w, ff2_w, ca_qkv_w + 512*512,
        qkvw_b, outw_b, ff1w_b, ff2w_b, kvw_b);

    // 1. byte embedding + n-gram hash adds
    embed_ngram_kernel<<<M, 128, 0, stream>>>(byte_seq, byte_emb, ng_emb, x, xb);

    // 2. transformer layers
    for (int l = 0; l < L_; ++l) {
        mgemm_kernel<0,1,128,1,0,0><<<dim3(1536/128, M/128), 256, 0, stream>>>(
            xb, qkvw_b + (size_t)l*1536*D_, qkv_b + l*1536, qkvb, vtb, nullptr, M, 1536, D_);
        attn_mfma_kernel<<<dim3(S_/128, B_*H_), 256, 0, stream>>>(qkvb, vtb, ob);
        mgemm_kernel<0,0,64,0,1,1><<<dim3(D_/64, M/128), 256, 0, stream>>>(
            ob, outw_b + (size_t)l*D_*D_, out_b + l*D_, bufB, nullptr, x, M, D_, D_);
        ln_kernel<<<M, 256, 0, stream>>>(x, xb, bufB, nullptr, ln1_w + l*D_, ln1_b + l*D_, 1e-5f);
        mgemm_kernel<1,1,128,0,0,0><<<dim3(2048/128, M/128), 256, 0, stream>>>(
            xb, ff1w_b + (size_t)l*2048*D_, ff1_b + l*2048, ff1b, nullptr, nullptr, M, 2048, D_);
        mgemm_kernel<0,0,64,0,1,1><<<dim3(D_/64, M/128), 256, 0, stream>>>(
            ff1b, ff2w_b + (size_t)l*D_*2048, ff2_b + l*D_, bufB, nullptr, x, M, D_, 2048);
        ln_kernel<<<M, 256, 0, stream>>>(x, xb, bufB, nullptr, ln2_w + l*D_, ln2_b + l*D_, 1e-5f);
    }

    // 3. dual LN (final out + kvn bf16, one pass) -> kv mgemm -> fused tail
    ln_dual_kernel<<<M, 256, 0, stream>>>(out, xb, x, norm_w, norm_b, ca_ln_w, ca_ln_b);
    mgemm_kernel<0,0,128,0,0,0><<<dim3(1024/128, M/128), 256, 0, stream>>>(
        xb, kvw_b, ca_qkv_b + 512, kvf, nullptr, nullptr, M, 1024, D_);
    patch_tail_kernel<<<B_*NPATCH_, 256, 0, stream>>>(
        x, kvf, ca_qkv_w, ca_qkv_b, ca_out_w, ca_out_b,
        ca_ln_w, ca_ln_b, norm_w, norm_b, out);
}

// Round 17
// 497.425 us; speedup vs baseline: 1.1000x; 1.0160x over previous
//
#include <hip/hip_runtime.h>
#include <hip/hip_bf16.h>

#define B_ 4
#define S_ 2048
#define D_ 512
#define H_ 8
#define HD_ 64
#define L_ 2
#define V_ 30000
#define NPATCH_ 16
#define PLEN_ 128

typedef short bf16x8 __attribute__((ext_vector_type(8)));
typedef float f32x4 __attribute__((ext_vector_type(4)));

__device__ __forceinline__ unsigned short f2bf(float f) {
    unsigned u = __float_as_uint(f);
    return (unsigned short)((u + 0x7FFFu + ((u >> 16) & 1u)) >> 16);   // RNE
}
__device__ __forceinline__ float bf2f(unsigned short u) {
    return __uint_as_float(((unsigned int)u) << 16);
}

// ---------------- merged f32 -> bf16 weight casts (1 launch) ----------------
#define C0_ (2*1536*512/4)
#define C1_ (2*512*512/4)
#define C2_ (2*2048*512/4)
#define C3_ (2*512*2048/4)
#define C4_ (1024*512/4)
__global__ __launch_bounds__(256) void cast5_kernel(
    const float* __restrict__ s0, const float* __restrict__ s1,
    const float* __restrict__ s2, const float* __restrict__ s3,
    const float* __restrict__ s4,
    unsigned short* __restrict__ d0, unsigned short* __restrict__ d1,
    unsigned short* __restrict__ d2, unsigned short* __restrict__ d3,
    unsigned short* __restrict__ d4)
{
    int i = blockIdx.x * 256 + threadIdx.x;
    const float* s; unsigned short* d;
    if      (i < C0_)                  { s = s0; d = d0; }
    else if ((i -= C0_) < C1_)         { s = s1; d = d1; }
    else if ((i -= C1_) < C2_)         { s = s2; d = d2; }
    else if ((i -= C2_) < C3_)         { s = s3; d = d3; }
    else if ((i -= C3_) < C4_)         { s = s4; d = d4; }
    else return;
    const float4 v = *reinterpret_cast<const float4*>(s + (size_t)i * 4);
    ushort4 o;
    o.x = f2bf(v.x); o.y = f2bf(v.y); o.z = f2bf(v.z); o.w = f2bf(v.w);
    *reinterpret_cast<ushort4*>(d + (size_t)i * 4) = o;
}

// ---------------- embed + n-gram hash add (f32 + bf16 shadow) -------------
__global__ __launch_bounds__(128) void embed_ngram_kernel(
    const int* __restrict__ bytes, const float* __restrict__ byte_emb,
    const float* __restrict__ ng_emb, float* __restrict__ x,
    unsigned short* __restrict__ xb)
{
    const int bs = blockIdx.x;
    const int s  = bs % S_;
    const int b  = bs / S_;
    const int d  = threadIdx.x * 4;
    const int* brow = bytes + (size_t)b * S_;

    const int c = brow[s];
    float4 v = *reinterpret_cast<const float4*>(byte_emb + (size_t)c * D_ + d);

    if (s >= 2) {
        int h = (brow[s-2]*961 + brow[s-1]*31 + brow[s]) % V_;
        const float4 g = *reinterpret_cast<const float4*>(ng_emb + ((size_t)0*V_ + h)*D_ + d);
        v.x += 0.25f*g.x; v.y += 0.25f*g.y; v.z += 0.25f*g.z; v.w += 0.25f*g.w;
    }
    if (s >= 3) {
        int h = (brow[s-3]*29791 + brow[s-2]*961 + brow[s-1]*31 + brow[s]) % V_;
        const float4 g = *reinterpret_cast<const float4*>(ng_emb + ((size_t)1*V_ + h)*D_ + d);
        v.x += 0.25f*g.x; v.y += 0.25f*g.y; v.z += 0.25f*g.z; v.w += 0.25f*g.w;
    }
    if (s >= 4) {
        int h = (brow[s-4]*23521 + brow[s-3]*29791 + brow[s-2]*961 + brow[s-1]*31 + brow[s]) % V_;
        const float4 g = *reinterpret_cast<const float4*>(ng_emb + ((size_t)2*V_ + h)*D_ + d);
        v.x += 0.25f*g.x; v.y += 0.25f*g.y; v.z += 0.25f*g.z; v.w += 0.25f*g.w;
    }
    *reinterpret_cast<float4*>(x + (size_t)bs * D_ + d) = v;
    ushort4 o;
    o.x = f2bf(v.x); o.y = f2bf(v.y); o.z = f2bf(v.z); o.w = f2bf(v.w);
    *reinterpret_cast<ushort4*>(xb + (size_t)bs * D_ + d) = o;
}

// ---------------- MFMA bf16 GEMM: Y = X @ W^T + bias [,relu][,+resid] ------
template<int DO_RELU, int BF16OUT, int BN, int VT, int RESID, int DBUF>
__global__ __launch_bounds__(256) void mgemm_kernel(
    const unsigned short* __restrict__ Xb, const unsigned short* __restrict__ Wb,
    const float* __restrict__ bias, void* __restrict__ Yout,
    unsigned short* __restrict__ vtb, const float* __restrict__ resid,
    int M, int N, int K)
{
    constexpr int NT  = BN / 32;
    constexpr int NLB = BN / 32;
    constexpr int NB  = DBUF ? 2 : 1;
    __shared__ unsigned short As[NB*128*64];
    __shared__ unsigned short Bs[NB*BN*64];

    const int t    = threadIdx.x;
    const int lane = t & 63;
    const int w    = t >> 6;

    const int nwg = gridDim.x * gridDim.y;
    const int bid = blockIdx.y * gridDim.x + blockIdx.x;
    const int swz = (bid & 7) * (nwg >> 3) + (bid >> 3);
    const int bx  = swz % gridDim.x, by = swz / gridDim.x;

    const int bm   = by * 128, bn = bx * BN;
    const int l15  = lane & 15, lg = lane >> 4;
    const int wr   = w >> 1, wc = w & 1;

    int srow[4], scol[4];
#pragma unroll
    for (int i = 0; i < 4; ++i) {
        const int off = w*1024 + i*4096 + lane*16;
        srow[i] = off >> 7;
        scol[i] = ((off >> 4) & 7) ^ (srow[i] & 7);
    }

    f32x4 acc[4][NT];
#pragma unroll
    for (int mt = 0; mt < 4; ++mt)
#pragma unroll
        for (int nt = 0; nt < NT; ++nt) acc[mt][nt] = (f32x4){0.f,0.f,0.f,0.f};

    auto STAGE = [&](int bufi, int kt) {
#pragma unroll
        for (int i = 0; i < 4; ++i) {
            const unsigned short* gA = Xb + (size_t)(bm + srow[i]) * K + kt + scol[i]*8;
            __builtin_amdgcn_global_load_lds(
                (const __attribute__((address_space(1))) void*)gA,
                (__attribute__((address_space(3))) void*)&As[bufi*128*64 + w*512 + i*2048], 16, 0, 0);
        }
#pragma unroll
        for (int i = 0; i < NLB; ++i) {
            const unsigned short* gB = Wb + (size_t)(bn + srow[i]) * K + kt + scol[i]*8;
            __builtin_amdgcn_global_load_lds(
                (const __attribute__((address_space(1))) void*)gB,
                (__attribute__((address_space(3))) void*)&Bs[bufi*BN*64 + w*512 + i*2048], 16, 0, 0);
        }
    };

    auto COMPUTE = [&](const unsigned short* Ab, const unsigned short* Bb) {
#pragma unroll
        for (int ks = 0; ks < 2; ++ks) {
            const int c16 = (ks*4 + lg) ^ (l15 & 7);
            bf16x8 a[4], b[NT];
#pragma unroll
            for (int mt = 0; mt < 4; ++mt)
                a[mt] = *reinterpret_cast<const bf16x8*>(&Ab[(wr*64 + mt*16 + l15)*64 + c16*8]);
#pragma unroll
            for (int nt = 0; nt < NT; ++nt)
                b[nt] = *reinterpret_cast<const bf16x8*>(&Bb[(wc*(BN/2) + nt*16 + l15)*64 + c16*8]);
#pragma unroll
            for (int mt = 0; mt < 4; ++mt)
#pragma unroll
                for (int nt = 0; nt < NT; ++nt)
                    acc[mt][nt] = __builtin_amdgcn_mfma_f32_16x16x32_bf16(
                        a[mt], b[nt], acc[mt][nt], 0, 0, 0);
        }
    };

    if constexpr (DBUF) {
        STAGE(0, 0);
        __syncthreads();
        const int niter = K >> 6;
        for (int it = 0; it < niter; ++it) {
            const int cur = it & 1;
            if (it + 1 < niter) STAGE(cur ^ 1, (it + 1) << 6);
            COMPUTE(&As[cur*128*64], &Bs[cur*BN*64]);
            __syncthreads();
        }
    } else {
        for (int kt = 0; kt < K; kt += 64) {
            STAGE(0, kt);
            __syncthreads();
            COMPUTE(As, Bs);
            __syncthreads();
        }
    }

    float bv[NT];
#pragma unroll
    for (int nt = 0; nt < NT; ++nt) bv[nt] = bias[bn + wc*(BN/2) + nt*16 + l15];

#pragma unroll
    for (int mt = 0; mt < 4; ++mt) {
#pragma unroll
        for (int nt = 0; nt < NT; ++nt) {
            const int n = bn + wc*(BN/2) + nt*16 + l15;
#pragma unroll
            for (int r = 0; r < 4; ++r) {
                const int m = bm + wr*64 + mt*16 + 4*lg + r;
                float v = acc[mt][nt][r] + bv[nt];
                if (DO_RELU) v = fmaxf(v, 0.f);
                if (RESID) v += resid[(size_t)m * N + n];
                if constexpr (VT) {
                    if (n < 1024)
                        ((unsigned short*)Yout)[(size_t)m * 1024 + n] = f2bf(v);
                    else
                        vtb[((size_t)(m >> 11) * 512 + (n - 1024)) * 2048 + (m & 2047)] = f2bf(v);
                } else if constexpr (BF16OUT) {
                    ((unsigned short*)Yout)[(size_t)m * N + n] = f2bf(v);
                } else {
                    ((float*)Yout)[(size_t)m * N + n] = v;
                }
            }
        }
    }
}

// ---------------- MFMA bf16 causal flash attention (round-13 proven) -------
__global__ __launch_bounds__(256) void attn_mfma_kernel(
    const unsigned short* __restrict__ qkvb, const unsigned short* __restrict__ vtb,
    unsigned short* __restrict__ ob)
{
    __shared__ unsigned short Ks[128*72];
    __shared__ unsigned short Vt[64*136];
    __shared__ unsigned short Plds[4*16*136];

    const int t    = threadIdx.x;
    const int lane = t & 63;
    const int w    = t >> 6;
    const int qp   = blockIdx.x;
    const int bh   = blockIdx.y;
    const int h    = bh & 7;
    const int b    = bh >> 3;

    const unsigned short* base = qkvb + (size_t)b * S_ * 1024;
    const int l15 = lane & 15, lg = lane >> 4;
    const int skey = t >> 1;
    const int sd0  = (t & 1) * 32;
    const int sdv  = t >> 2;
    const int skc  = (t & 3) * 32;
    const unsigned short* vbase = vtb + ((size_t)b * 512 + h*64 + sdv) * 2048;
    unsigned short* pw_base = Plds + w*16*136;
    const int pxor = ((l15 >> 3) & 1) << 1;

    bf16x8 kr0, kr1, kr2, kr3, vr0, vr1, vr2, vr3;
#define LOADREG(KT) { \
        const unsigned short* pk_ = base + (size_t)((KT) + skey) * 1024 + 512 + h*64 + sd0; \
        kr0 = *reinterpret_cast<const bf16x8*>(pk_);       \
        kr1 = *reinterpret_cast<const bf16x8*>(pk_ + 8);   \
        kr2 = *reinterpret_cast<const bf16x8*>(pk_ + 16);  \
        kr3 = *reinterpret_cast<const bf16x8*>(pk_ + 24);  \
        const unsigned short* pv_ = vbase + (KT) + skc;    \
        vr0 = *reinterpret_cast<const bf16x8*>(pv_);       \
        vr1 = *reinterpret_cast<const bf16x8*>(pv_ + 8);   \
        vr2 = *reinterpret_cast<const bf16x8*>(pv_ + 16);  \
        vr3 = *reinterpret_cast<const bf16x8*>(pv_ + 24); }

    LOADREG(0);

#pragma unroll
    for (int half = 0; half < 2; ++half) {
        const int qb  = half ? (31 - qp) : qp;
        const int q0w = qb * 64 + w * 16;

        bf16x8 qf0, qf1;
        {
            const unsigned short* qr = base + (size_t)(q0w + l15) * 1024 + h*64 + lg*8;
            qf0 = *reinterpret_cast<const bf16x8*>(qr);
            qf1 = *reinterpret_cast<const bf16x8*>(qr + 32);
        }

        f32x4 oacc[4];
#pragma unroll
        for (int i = 0; i < 4; ++i) oacc[i] = (f32x4){0.f,0.f,0.f,0.f};
        float mrow[4] = {-INFINITY,-INFINITY,-INFINITY,-INFINITY};
        float lrow[4] = {0.f,0.f,0.f,0.f};

        const int ntiles = (qb + 2) >> 1;
        for (int tile = 0; tile < ntiles; ++tile) {
            const int kt = tile * 128;
            __syncthreads();
            *reinterpret_cast<bf16x8*>(&Ks[skey*72 + sd0])      = kr0;
            *reinterpret_cast<bf16x8*>(&Ks[skey*72 + sd0 + 8])  = kr1;
            *reinterpret_cast<bf16x8*>(&Ks[skey*72 + sd0 + 16]) = kr2;
            *reinterpret_cast<bf16x8*>(&Ks[skey*72 + sd0 + 24]) = kr3;
            *reinterpret_cast<bf16x8*>(&Vt[sdv*136 + skc])      = vr0;
            *reinterpret_cast<bf16x8*>(&Vt[sdv*136 + skc + 8])  = vr1;
            *reinterpret_cast<bf16x8*>(&Vt[sdv*136 + skc + 16]) = vr2;
            *reinterpret_cast<bf16x8*>(&Vt[sdv*136 + skc + 24]) = vr3;
            __syncthreads();
            const int nkt = (tile + 1 < ntiles) ? (kt + 128) : 0;
            LOADREG(nkt);

            f32x4 sacc[8];
            __builtin_amdgcn_s_setprio(1);
#pragma unroll
            for (int kt16 = 0; kt16 < 8; ++kt16) {
                sacc[kt16] = (f32x4){0.f,0.f,0.f,0.f};
                const unsigned short* kp = &Ks[(kt16*16 + l15)*72 + lg*8];
                bf16x8 k0 = *reinterpret_cast<const bf16x8*>(kp);
                bf16x8 k1 = *reinterpret_cast<const bf16x8*>(kp + 32);
                sacc[kt16] = __builtin_amdgcn_mfma_f32_16x16x32_bf16(qf0, k0, sacc[kt16], 0, 0, 0);
                sacc[kt16] = __builtin_amdgcn_mfma_f32_16x16x32_bf16(qf1, k1, sacc[kt16], 0, 0, 0);
            }
            __builtin_amdgcn_s_setprio(0);

            const bool diag = (tile == ntiles - 1);
#pragma unroll
            for (int kt16 = 0; kt16 < 8; ++kt16) {
#pragma unroll
                for (int r = 0; r < 4; ++r) {
                    float s = sacc[kt16][r] * 0.125f;
                    if (diag) {
                        const int key = kt + kt16*16 + l15;
                        const int q   = q0w + 4*lg + r;
                        if (key > q) s = -INFINITY;
                    }
                    sacc[kt16][r] = s;
                }
            }
#pragma unroll
            for (int r = 0; r < 4; ++r) {
                float tm = fmaxf(
                    fmaxf(fmaxf(sacc[0][r], sacc[1][r]), fmaxf(sacc[2][r], sacc[3][r])),
                    fmaxf(fmaxf(sacc[4][r], sacc[5][r]), fmaxf(sacc[6][r], sacc[7][r])));
#pragma unroll
                for (int off = 8; off; off >>= 1) tm = fmaxf(tm, __shfl_xor(tm, off, 64));
                const float nm = fmaxf(mrow[r], tm);
                const float al = __expf(mrow[r] - nm);
                mrow[r] = nm;
                float ps = 0.f;
                const int prow = (4*lg + r)*136;
                const int cswz = ((lg & 2) << 3);
#pragma unroll
                for (int kt16 = 0; kt16 < 8; ++kt16) {
                    const float p = __expf(sacc[kt16][r] - nm);
                    ps += p;
                    pw_base[prow + ((kt16*16 + l15) ^ cswz)] = f2bf(p);
                }
#pragma unroll
                for (int off = 8; off; off >>= 1) ps += __shfl_xor(ps, off, 64);
                lrow[r] = lrow[r]*al + ps;
#pragma unroll
                for (int dt = 0; dt < 4; ++dt) oacc[dt][r] *= al;
            }

            const unsigned short* pr = &pw_base[l15*136];
            bf16x8 pa0 = *reinterpret_cast<const bf16x8*>(&pr[(( 0 + lg) ^ pxor)*8]);
            bf16x8 pa1 = *reinterpret_cast<const bf16x8*>(&pr[(( 4 + lg) ^ pxor)*8]);
            bf16x8 pa2 = *reinterpret_cast<const bf16x8*>(&pr[(( 8 + lg) ^ pxor)*8]);
            bf16x8 pa3 = *reinterpret_cast<const bf16x8*>(&pr[((12 + lg) ^ pxor)*8]);
            __builtin_amdgcn_s_setprio(1);
#pragma unroll
            for (int dt = 0; dt < 4; ++dt) {
                const unsigned short* vrow = &Vt[(dt*16 + l15)*136];
                bf16x8 v0 = *reinterpret_cast<const bf16x8*>(&vrow[( 0 + lg)*8]);
                bf16x8 v1 = *reinterpret_cast<const bf16x8*>(&vrow[( 4 + lg)*8]);
                bf16x8 v2 = *reinterpret_cast<const bf16x8*>(&vrow[( 8 + lg)*8]);
                bf16x8 v3 = *reinterpret_cast<const bf16x8*>(&vrow[(12 + lg)*8]);
                oacc[dt] = __builtin_amdgcn_mfma_f32_16x16x32_bf16(pa0, v0, oacc[dt], 0, 0, 0);
                oacc[dt] = __builtin_amdgcn_mfma_f32_16x16x32_bf16(pa1, v1, oacc[dt], 0, 0, 0);
                oacc[dt] = __builtin_amdgcn_mfma_f32_16x16x32_bf16(pa2, v2, oacc[dt], 0, 0, 0);
                oacc[dt] = __builtin_amdgcn_mfma_f32_16x16x32_bf16(pa3, v3, oacc[dt], 0, 0, 0);
            }
            __builtin_amdgcn_s_setprio(0);
        }

#pragma unroll
        for (int dt = 0; dt < 4; ++dt) {
#pragma unroll
            for (int r = 0; r < 4; ++r) {
                const int q = q0w + 4*lg + r;
                ob[((size_t)b*S_ + q)*D_ + h*64 + dt*16 + l15] = f2bf(oacc[dt][r] / lrow[r]);
            }
        }
    }
#undef LOADREG
}

// ---------------- LayerNorm (residual add, nullable outputs) ---------------
__global__ __launch_bounds__(256) void ln_kernel(
    float* __restrict__ dst, unsigned short* __restrict__ dst2,
    const float* __restrict__ src, const float* __restrict__ add,
    const float* __restrict__ w, const float* __restrict__ b, float eps)
{
    const int row = blockIdx.x, tid = threadIdx.x;
    const int lane = tid & 63, wave = tid >> 6;
    float2 v = *reinterpret_cast<const float2*>(src + (size_t)row * D_ + tid*2);
    if (add) {
        float2 a = *reinterpret_cast<const float2*>(add + (size_t)row * D_ + tid*2);
        v.x += a.x; v.y += a.y;
    }
    __shared__ float red[8];
    float s = v.x + v.y;
#pragma unroll
    for (int off = 32; off; off >>= 1) s += __shfl_xor(s, off, 64);
    if (lane == 0) red[wave] = s;
    __syncthreads();
    const float mean = (red[0]+red[1]+red[2]+red[3]) * (1.f/D_);
    const float d0 = v.x - mean, d1 = v.y - mean;
    float sq = d0*d0 + d1*d1;
#pragma unroll
    for (int off = 32; off; off >>= 1) sq += __shfl_xor(sq, off, 64);
    if (lane == 0) red[4+wave] = sq;
    __syncthreads();
    const float var = (red[4]+red[5]+red[6]+red[7]) * (1.f/D_);
    const float inv = rsqrtf(var + eps);
    const float o0 = d0*inv*w[tid*2] + b[tid*2];
    const float o1 = d1*inv*w[tid*2+1] + b[tid*2+1];
    if (dst)
        *reinterpret_cast<float2*>(dst + (size_t)row * D_ + tid*2) = make_float2(o0, o1);
    if (dst2) {
        ushort2 u; u.x = f2bf(o0); u.y = f2bf(o1);
        *reinterpret_cast<ushort2*>(dst2 + (size_t)row * D_ + tid*2) = u;
    }
}

// ---------------- dual LayerNorm: one read of x -> final out (f32) + kvn (bf16)
__global__ __launch_bounds__(256) void ln_dual_kernel(
    float* __restrict__ out, unsigned short* __restrict__ kvnb,
    const float* __restrict__ src,
    const float* __restrict__ nw, const float* __restrict__ nb,
    const float* __restrict__ cw, const float* __restrict__ cb)
{
    const int row = blockIdx.x, tid = threadIdx.x;
    const int lane = tid & 63, wave = tid >> 6;
    float2 v = *reinterpret_cast<const float2*>(src + (size_t)row * D_ + tid*2);
    __shared__ float red[8];
    float s = v.x + v.y;
#pragma unroll
    for (int off = 32; off; off >>= 1) s += __shfl_xor(s, off, 64);
    if (lane == 0) red[wave] = s;
    __syncthreads();
    const float mean = (red[0]+red[1]+red[2]+red[3]) * (1.f/D_);
    const float d0 = v.x - mean, d1 = v.y - mean;
    float sq = d0*d0 + d1*d1;
#pragma unroll
    for (int off = 32; off; off >>= 1) sq += __shfl_xor(sq, off, 64);
    if (lane == 0) red[4+wave] = sq;
    __syncthreads();
    const float var = (red[4]+red[5]+red[6]+red[7]) * (1.f/D_);
    const float inv = rsqrtf(var + 1e-6f);
    const float n0 = d0*inv;
    const float n1 = d1*inv;
    *reinterpret_cast<float2*>(out + (size_t)row * D_ + tid*2) =
        make_float2(n0*nw[tid*2] + nb[tid*2], n1*nw[tid*2+1] + nb[tid*2+1]);
    ushort2 u;
    u.x = f2bf(n0*cw[tid*2]   + cb[tid*2]);
    u.y = f2bf(n1*cw[tid*2+1] + cb[tid*2+1]);
    *reinterpret_cast<ushort2*>(kvnb + (size_t)row * D_ + tid*2) = u;
}

// ---------------- fused patch-CA tail (bf16 K/V) ----------------
__global__ __launch_bounds__(256) void patch_tail_kernel(
    const float* __restrict__ x, const unsigned short* __restrict__ kvb,
    const float* __restrict__ ca_qkv_w, const float* __restrict__ ca_qkv_b,
    const float* __restrict__ ca_out_w, const float* __restrict__ ca_out_b,
    const float* __restrict__ ca_ln_w, const float* __restrict__ ca_ln_b,
    const float* __restrict__ norm_w, const float* __restrict__ norm_b,
    float* __restrict__ out)
{
    __shared__ float query[512];
    __shared__ float qs[512];
    __shared__ float ps[8*128];
    __shared__ float os[512];
    __shared__ float red[64];
    __shared__ float mred[8], sred[8];

    const int t  = threadIdx.x;
    const int bp = blockIdx.x;
    const int d0 = t * 2;
    const int lane = t & 63, wave = t >> 6;

    {
        const float* base = x + (size_t)bp * PLEN_ * D_ + d0;
        float s0 = 0.f, s1 = 0.f;
        for (int l = 0; l < PLEN_; ++l) {
            float2 v = *reinterpret_cast<const float2*>(base + (size_t)l * D_);
            s0 += v.x; s1 += v.y;
        }
        query[d0] = s0 * (1.f/PLEN_);
        query[d0+1] = s1 * (1.f/PLEN_);
    }
    __syncthreads();

    float qv0 = query[d0], qv1 = query[d0+1];
    {
        float s = qv0 + qv1;
#pragma unroll
        for (int off = 32; off; off >>= 1) s += __shfl_xor(s, off, 64);
        if (lane == 0) red[wave] = s;
        __syncthreads();
        const float mean = (red[0]+red[1]+red[2]+red[3]) * (1.f/D_);
        const float e0 = qv0 - mean, e1 = qv1 - mean;
        float sq = e0*e0 + e1*e1;
#pragma unroll
        for (int off = 32; off; off >>= 1) sq += __shfl_xor(sq, off, 64);
        if (lane == 0) red[4+wave] = sq;
        __syncthreads();
        const float var = (red[4]+red[5]+red[6]+red[7]) * (1.f/D_);
        const float inv = rsqrtf(var + 1e-6f);
        qs[d0]   = e0*inv*ca_ln_w[d0]   + ca_ln_b[d0];
        qs[d0+1] = e1*inv*ca_ln_w[d0+1] + ca_ln_b[d0+1];
    }
    __syncthreads();

    float qp0, qp1;
    {
        const float* w0 = ca_qkv_w + (size_t)d0 * D_;
        float a0 = ca_qkv_b[d0], a1 = ca_qkv_b[d0+1];
        for (int e = 0; e < D_; e += 4) {
            const float4 qn4 = *reinterpret_cast<const float4*>(&qs[e]);
            const float4 wa = *reinterpret_cast<const float4*>(w0 + e);
            const float4 wb = *reinterpret_cast<const float4*>(w0 + D_ + e);
            a0 += qn4.x*wa.x + qn4.y*wa.y + qn4.z*wa.z + qn4.w*wa.w;
            a1 += qn4.x*wb.x + qn4.y*wb.y + qn4.z*wb.z + qn4.w*wb.w;
        }
        qp0 = a0 * 0.125f; qp1 = a1 * 0.125f;
    }
    __syncthreads();
    qs[d0] = qp0; qs[d0+1] = qp1;
    __syncthreads();

    {
        const int h = t >> 5, c = t & 31;
        const float* qh = &qs[h*64];
#pragma unroll
        for (int j = 0; j < 4; ++j) {
            const int l = c*4 + j;
            const unsigned short* krow = kvb + ((size_t)bp*PLEN_ + l)*1024 + h*64;
            float acc = 0.f;
            for (int e = 0; e < 64; e += 8) {
                bf16x8 k8 = *reinterpret_cast<const bf16x8*>(krow + e);
#pragma unroll
                for (int jj = 0; jj < 8; ++jj)
                    acc += qh[e+jj] * bf2f((unsigned short)k8[jj]);
            }
            ps[h*128 + l] = acc;
        }
    }
    __syncthreads();

    {
        const int h = t >> 5, c = t & 31;
        float m4 = fmaxf(fmaxf(ps[h*128+c*4], ps[h*128+c*4+1]),
                         fmaxf(ps[h*128+c*4+2], ps[h*128+c*4+3]));
        red[h*8 + (c>>2)] = 0.f;
        __syncthreads();
        float mt_ = m4;
#pragma unroll
        for (int off = 1; off < 4; off <<= 1) mt_ = fmaxf(mt_, __shfl_xor(mt_, off, 64));
        if ((c & 3) == 0) red[h*8 + (c>>2)] = mt_;
        __syncthreads();
        if (t < 8) {
            float m = red[t*8];
#pragma unroll
            for (int j = 1; j < 8; ++j) m = fmaxf(m, red[t*8+j]);
            mred[t] = m;
        }
        __syncthreads();
        const float mh = mred[h];
        float ssum = 0.f;
#pragma unroll
        for (int j = 0; j < 4; ++j) {
            const float p = __expf(ps[h*128 + c*4 + j] - mh);
            ps[h*128 + c*4 + j] = p;
            ssum += p;
        }
#pragma unroll
        for (int off = 1; off < 4; off <<= 1) ssum += __shfl_xor(ssum, off, 64);
        if ((c & 3) == 0) red[h*8 + (c>>2)] = ssum;
        __syncthreads();
        if (t < 8) {
            float s = 0.f;
#pragma unroll
            for (int j = 0; j < 8; ++j) s += red[t*8+j];
            sred[t] = 1.f / s;
        }
    }
    __syncthreads();

    {
        const int h = t >> 5;
        const unsigned short* vbase = kvb + (size_t)bp*PLEN_*1024 + 512 + d0;
        float a0 = 0.f, a1 = 0.f;
        const float* ph = &ps[h*128];
        for (int l = 0; l < PLEN_; ++l) {
            const float p = ph[l];
            const ushort2 vv = *reinterpret_cast<const ushort2*>(vbase + (size_t)l*1024);
            a0 += p * bf2f(vv.x); a1 += p * bf2f(vv.y);
        }
        os[d0]   = a0 * sred[h];
        os[d0+1] = a1 * sred[h];
    }
    __syncthreads();

    float r0, r1;
    {
        const float* w0 = ca_out_w + (size_t)d0 * D_;
        float a0 = ca_out_b[d0], a1 = ca_out_b[d0+1];
        for (int e = 0; e < D_; e += 4) {
            const float4 oe = *reinterpret_cast<const float4*>(&os[e]);
            const float4 wa = *reinterpret_cast<const float4*>(w0 + e);
            const float4 wb = *reinterpret_cast<const float4*>(w0 + D_ + e);
            a0 += oe.x*wa.x + oe.y*wa.y + oe.z*wa.z + oe.w*wa.w;
            a1 += oe.x*wb.x + oe.y*wb.y + oe.z*wb.z + oe.w*wb.w;
        }
        r0 = query[d0] + a0;
        r1 = query[d0+1] + a1;
    }
    {
        float s = r0 + r1;
#pragma unroll
        for (int off = 32; off; off >>= 1) s += __shfl_xor(s, off, 64);
        __syncthreads();
        if (lane == 0) red[wave] = s;
        __syncthreads();
        const float mean = (red[0]+red[1]+red[2]+red[3]) * (1.f/D_);
        const float e0 = r0 - mean, e1 = r1 - mean;
        float sq = e0*e0 + e1*e1;
#pragma unroll
        for (int off = 32; off; off >>= 1) sq += __shfl_xor(sq, off, 64);
        if (lane == 0) red[4+wave] = sq;
        __syncthreads();
        const float var = (red[4]+red[5]+red[6]+red[7]) * (1.f/D_);
        const float inv = rsqrtf(var + 1e-6f);
        float* orow = out + ((size_t)(B_*S_) + bp) * D_;
        orow[d0]   = e0*inv*norm_w[d0]   + norm_b[d0];
        orow[d0+1] = e1*inv*norm_w[d0+1] + norm_b[d0+1];
    }
}

extern "C" void kernel_launch(void* const* d_in, const int* in_sizes, int n_in,
                              void* d_out, int out_size, void* d_ws, size_t ws_size,
                              hipStream_t stream)
{
    const int*   byte_seq = (const int*)d_in[0];
    const float* byte_emb = (const float*)d_in[2];
    const float* ng_emb   = (const float*)d_in[3];
    const float* qkv_w = (const float*)d_in[4];
    const float* qkv_b = (const float*)d_in[5];
    const float* out_w = (const float*)d_in[6];
    const float* out_b = (const float*)d_in[7];
    const float* ln1_w = (const float*)d_in[8];
    const float* ln1_b = (const float*)d_in[9];
    const float* ln2_w = (const float*)d_in[10];
    const float* ln2_b = (const float*)d_in[11];
    const float* ff1_w = (const float*)d_in[12];
    const float* ff1_b = (const float*)d_in[13];
    const float* ff2_w = (const float*)d_in[14];
    const float* ff2_b = (const float*)d_in[15];
    const float* ca_qkv_w = (const float*)d_in[16];
    const float* ca_qkv_b = (const float*)d_in[17];
    const float* ca_out_w = (const float*)d_in[18];
    const float* ca_out_b = (const float*)d_in[19];
    const float* ca_ln_w  = (const float*)d_in[20];
    const float* ca_ln_b  = (const float*)d_in[21];
    const float* norm_w   = (const float*)d_in[22];
    const float* norm_b   = (const float*)d_in[23];
    float* out = (float*)d_out;

    char* ws = (char*)d_ws;
    const size_t MB = 1024*1024;
    float*          x     = (float*)(ws);                    // [0,16M)
    char*           bufA  = ws + 16*MB;                      // [16,48M) qkvb/ff1b/kvb
    float*          bufB  = (float*)(ws + 48*MB);            // [48,64M) proj/ff2 f32
    unsigned short* vtb   = (unsigned short*)(ws + 48*MB);   // aliases bufB (disjoint lifetime)
    unsigned short* ob    = (unsigned short*)(ws + 64*MB);   // [64,72M)
    unsigned short* xb    = (unsigned short*)(ws + 72*MB);   // [72,80M)
    unsigned short* qkvw_b = (unsigned short*)(ws + 80*MB);
    unsigned short* outw_b = (unsigned short*)(ws + 83*MB);
    unsigned short* ff1w_b = (unsigned short*)(ws + 84*MB);
    unsigned short* ff2w_b = (unsigned short*)(ws + 88*MB);
    unsigned short* kvw_b  = (unsigned short*)(ws + 92*MB);

    unsigned short* qkvb = (unsigned short*)bufA;   // bf16 [8192][1024] ([q|k])
    unsigned short* ff1b = (unsigned short*)bufA;   // bf16 [8192][2048]
    unsigned short* kvb  = (unsigned short*)bufA;   // bf16 [8192][1024] (patch K/V)

    const int M = B_ * S_;

    // 0. one-time weight casts to bf16 (single launch)
    cast5_kernel<<<(C0_+C1_+C2_+C3_+C4_+255)/256, 256, 0, stream>>>(
        qkv_w, out_w, ff1_w, ff2_w, ca_qkv_w + 512*512,
        qkvw_b, outw_b, ff1w_b, ff2w_b, kvw_b);

    // 1. byte embedding + n-gram hash adds
    embed_ngram_kernel<<<M, 128, 0, stream>>>(byte_seq, byte_emb, ng_emb, x, xb);

    // 2. transformer layers
    for (int l = 0; l < L_; ++l) {
        mgemm_kernel<0,1,128,1,0,0><<<dim3(1536/128, M/128), 256, 0, stream>>>(
            xb, qkvw_b + (size_t)l*1536*D_, qkv_b + l*1536, qkvb, vtb, nullptr, M, 1536, D_);
        attn_mfma_kernel<<<dim3(S_/128, B_*H_), 256, 0, stream>>>(qkvb, vtb, ob);
        mgemm_kernel<0,0,64,0,1,1><<<dim3(D_/64, M/128), 256, 0, stream>>>(
            ob, outw_b + (size_t)l*D_*D_, out_b + l*D_, bufB, nullptr, x, M, D_, D_);
        ln_kernel<<<M, 256, 0, stream>>>(x, xb, bufB, nullptr, ln1_w + l*D_, ln1_b + l*D_, 1e-5f);
        mgemm_kernel<1,1,128,0,0,0><<<dim3(2048/128, M/128), 256, 0, stream>>>(
            xb, ff1w_b + (size_t)l*2048*D_, ff1_b + l*2048, ff1b, nullptr, nullptr, M, 2048, D_);
        mgemm_kernel<0,0,64,0,1,1><<<dim3(D_/64, M/128), 256, 0, stream>>>(
            ff1b, ff2w_b + (size_t)l*D_*2048, ff2_b + l*D_, bufB, nullptr, x, M, D_, 2048);
        ln_kernel<<<M, 256, 0, stream>>>(x, xb, bufB, nullptr, ln2_w + l*D_, ln2_b + l*D_, 1e-5f);
    }

    // 3. dual LN (final out + kvn bf16) -> kv mgemm (bf16 out) -> fused tail
    ln_dual_kernel<<<M, 256, 0, stream>>>(out, xb, x, norm_w, norm_b, ca_ln_w, ca_ln_b);
    mgemm_kernel<0,1,128,0,0,0><<<dim3(1024/128, M/128), 256, 0, stream>>>(
        xb, kvw_b, ca_qkv_b + 512, kvb, nullptr, nullptr, M, 1024, D_);
    patch_tail_kernel<<<B_*NPATCH_, 256, 0, stream>>>(
        x, kvb, ca_qkv_w, ca_qkv_b, ca_out_w, ca_out_b,
        ca_ln_w, ca_ln_b, norm_w, norm_b, out);
}